// Round 8
// baseline (723.189 us; speedup 1.0000x reference)
//
#include <hip/hip_runtime.h>
#include <hip/hip_bf16.h>
#include <math.h>

#define N_NODES 50000
#define N_EDGES 800000
#define N_GRAPHS 512
#define F_IN 16
#define E_DIM 64
#define D 128
#define L_DIM 64
#define NEG_SLOPE 0.01f

#define SCAN_N (N_NODES + 1)                  // 50001
#define NBUCK ((N_NODES + 127) >> 7)          // 391 buckets of 128 nodes
#define EPT 4
#define BFT 1024
#define EPB (BFT * EPT)                       // 4096 edges per block
#define NT64 ((N_NODES + 63) / 64)            // 782 row tiles of 64

typedef __hip_bfloat16 bf16;
typedef unsigned int uint;
typedef unsigned short ushort;
typedef __attribute__((ext_vector_type(8))) short short8;
typedef __attribute__((ext_vector_type(4))) float float4v;

__device__ __forceinline__ float b2f(bf16 v) { return __bfloat162float(v); }
__device__ __forceinline__ bf16  f2b(float v) { return __float2bfloat16(v); }
__device__ __forceinline__ short f2bs(float f) { bf16 b = __float2bfloat16(f); return *reinterpret_cast<short*>(&b); }
__device__ __forceinline__ float bs2f(short s) { return __uint_as_float(((uint)(ushort)s) << 16); }
__device__ __forceinline__ float leaky(float v) { return v > 0.f ? v : NEG_SLOPE * v; }

// fast transcendentals: v_exp_f32 / v_rcp_f32 based.
__device__ __forceinline__ float frcp(float x) { return __builtin_amdgcn_rcpf(x); }
__device__ __forceinline__ float sigm(float v) { return frcp(1.f + __expf(-v)); }
__device__ __forceinline__ float ftanh(float v)
{
    v = fminf(15.f, fmaxf(-15.f, v));
    float a = __expf(2.f * v);
    return (a - 1.f) * frcp(a + 1.f);
}

// ---------------------------------------------------------------------------
__global__ __launch_bounds__(256) void k_signal(float* outp, int n)
{
    int i = blockIdx.x * 256 + threadIdx.x;
    if (i < n) outp[i] = 1.0f;
}

// ---------------------------------------------------------------------------
// h0 = leaky(leaky(x@W_emb + b_emb) @ W_first + b_first)  -> bf16
// ---------------------------------------------------------------------------
#define NPE 16
__global__ __launch_bounds__(128) void k_embed(
    const float* __restrict__ x, const float* __restrict__ Wemb, const float* __restrict__ bemb,
    const float* __restrict__ Wfirst, const float* __restrict__ bfirst, bf16* __restrict__ out)
{
    __shared__ float xs[NPE][F_IN];
    __shared__ float ys[NPE][E_DIM];
    int t = threadIdx.x;
    int base = blockIdx.x * NPE;

    for (int i = t; i < NPE * F_IN; i += 128)
        xs[i / F_IN][i % F_IN] = x[(size_t)base * F_IN + i];
    __syncthreads();

    if (t < E_DIM) {
        float acc[NPE];
#pragma unroll
        for (int nn = 0; nn < NPE; nn++) acc[nn] = 0.f;
        for (int k = 0; k < F_IN; k++) {
            float w = Wemb[k * E_DIM + t];
#pragma unroll
            for (int nn = 0; nn < NPE; nn++) acc[nn] += xs[nn][k] * w;
        }
        float bb = bemb[t];
#pragma unroll
        for (int nn = 0; nn < NPE; nn++) ys[nn][t] = leaky(acc[nn] + bb);
    }
    __syncthreads();

    {
        float acc[NPE];
#pragma unroll
        for (int nn = 0; nn < NPE; nn++) acc[nn] = 0.f;
        for (int k = 0; k < E_DIM; k++) {
            float w = Wfirst[k * D + t];
#pragma unroll
            for (int nn = 0; nn < NPE; nn++) acc[nn] += ys[nn][k] * w;
        }
        float bb = bfirst[t];
#pragma unroll
        for (int nn = 0; nn < NPE; nn++)
            out[(size_t)(base + nn) * D + t] = f2b(leaky(acc[nn] + bb));
    }
}

// ---------------------------------------------------------------------------
// Bucketed CSR build.
// ---------------------------------------------------------------------------
__global__ __launch_bounds__(256) void k_bcount(const int* __restrict__ ei, int* __restrict__ bcnt)
{
    __shared__ int lc[NBUCK];
    for (int i = threadIdx.x; i < NBUCK; i += 256) lc[i] = 0;
    __syncthreads();
    int stride = gridDim.x * 256;
    for (int e = blockIdx.x * 256 + threadIdx.x; e < N_EDGES; e += stride) {
        int d = ei[N_EDGES + e];
        d = d < 0 ? 0 : (d >= N_NODES ? N_NODES - 1 : d);
        atomicAdd(&lc[d >> 7], 1);
    }
    __syncthreads();
    for (int i = threadIdx.x; i < NBUCK; i += 256)
        if (lc[i]) atomicAdd(&bcnt[i + 1], lc[i]);
}

__global__ void k_bscan(int* __restrict__ bcnt)
{
    if (threadIdx.x == 0 && blockIdx.x == 0) {
        int run = 0;
        for (int i = 0; i <= NBUCK; i++) { run += bcnt[i]; bcnt[i] = run; }
    }
}

__global__ __launch_bounds__(BFT) void k_bfill2(
    const int* __restrict__ ei, const int* __restrict__ bstart,
    int* __restrict__ bcur, uint* __restrict__ ebuf)
{
    __shared__ int lcnt[NBUCK];
    __shared__ int lbase[NBUCK];
    int t = threadIdx.x;
    int e0 = blockIdx.x * EPB;

    for (int i = t; i < NBUCK; i += BFT) lcnt[i] = 0;
    __syncthreads();

    uint pk[EPT];
    int bb[EPT];
#pragma unroll
    for (int q = 0; q < EPT; q++) {
        int e = e0 + q * BFT + t;          // coalesced reads
        bb[q] = -1;
        if (e < N_EDGES) {
            int s = ei[e];
            int d = ei[N_EDGES + e];
            s = s < 0 ? 0 : (s >= N_NODES ? N_NODES - 1 : s);
            d = d < 0 ? 0 : (d >= N_NODES ? N_NODES - 1 : d);
            bb[q] = d >> 7;
            pk[q] = ((uint)(d & 127) << 16) | (uint)s;
            atomicAdd(&lcnt[bb[q]], 1);    // LDS atomic (fast)
        }
    }
    __syncthreads();

    for (int i = t; i < NBUCK; i += BFT) {
        int cv = lcnt[i];
        lbase[i] = cv > 0 ? atomicAdd(&bcur[i], cv) : 0;
    }
    __syncthreads();
    for (int i = t; i < NBUCK; i += BFT) lcnt[i] = 0;   // reuse as cursor
    __syncthreads();

#pragma unroll
    for (int q = 0; q < EPT; q++) {
        if (bb[q] >= 0) {
            int pos = lbase[bb[q]] + atomicAdd(&lcnt[bb[q]], 1);
            int slot = bstart[bb[q]] + pos;
            if (slot >= 0 && slot < N_EDGES) ebuf[slot] = pk[q];
        }
    }
}

__global__ __launch_bounds__(256) void k_csr(
    const int* __restrict__ bstart, const uint* __restrict__ ebuf,
    int* __restrict__ offs, int* __restrict__ srcs)
{
    __shared__ int cnt[128];
    __shared__ int loffs[129];
    int b = blockIdx.x, t = threadIdx.x;
    int e0 = bstart[b], e1 = bstart[b + 1];
    if (t < 128) cnt[t] = 0;
    __syncthreads();
    for (int j = e0 + t; j < e1; j += 256)
        atomicAdd(&cnt[(ebuf[j] >> 16) & 127], 1);
    __syncthreads();
    if (t == 0) {
        int run = 0;
        for (int i = 0; i < 128; i++) { loffs[i] = run; run += cnt[i]; }
        loffs[128] = run;
    }
    __syncthreads();
    int n0 = b << 7;
    if (t < 128) {
        int n = n0 + t;
        if (n <= N_NODES) offs[n] = e0 + loffs[t];
        cnt[t] = 0;
    }
    __syncthreads();
    for (int j = e0 + t; j < e1; j += 256) {
        uint pk = ebuf[j];
        int dl = (pk >> 16) & 127;
        int rank = atomicAdd(&cnt[dl], 1);
        int slot = e0 + loffs[dl] + rank;
        if (slot >= 0 && slot < N_EDGES) srcs[slot] = (int)(pk & 0xffffu);
    }
}

// ---------------------------------------------------------------------------
__global__ __launch_bounds__(256) void k_gstart(const int* __restrict__ batch, int* __restrict__ gstart)
{
    int g = blockIdx.x * 256 + threadIdx.x;
    if (g > N_GRAPHS) return;
    int lo = 0, hi = N_NODES;
    while (lo < hi) {
        int mid = (lo + hi) >> 1;
        if (batch[mid] < g) lo = mid + 1; else hi = mid;
    }
    gstart[g] = lo;
}

// ---------------------------------------------------------------------------
// Weight packing.
//   W1p : frag f = ct*8 + k0, 512 shorts/frag (k = kb*32+(l>>4)*8+j, n = ct*16+(l&15))
//   W2p : merged [Wih;Whh], frag f = ph*8 + k0; ph = ct*3 + p; k0<4 from Wih
//         (k = k0*32+...), k0>=4 from Whh (k=(k0-4)*32+...); n = p*128+ct*16+(l&15)
// ---------------------------------------------------------------------------
__global__ __launch_bounds__(256) void k_pack_all(
    const float* __restrict__ Wl, const float* __restrict__ Wr,
    const float* __restrict__ gWih, const float* __restrict__ gWhh,
    short* __restrict__ W1p, short* __restrict__ W2p)
{
    int tid = blockIdx.x * 256 + threadIdx.x;     // 131072 total
    if (tid < 32768) {
        int j = tid & 7, l = (tid >> 3) & 63, frag = tid >> 9;
        int nb = frag >> 3, kb = frag & 7;        // frag = ct*8 + k0
        int k = kb * 32 + ((l >> 4) * 8) + j;
        int n = nb * 16 + (l & 15);
        float v = (k < 128) ? Wl[k * D + n] : Wr[(k - 128) * D + n];
        W1p[tid] = f2bs(v);
    } else {
        int id = tid - 32768;                     // [0, 98304)
        int j = id & 7, l = (id >> 3) & 63, f = id >> 9;   // f in [0,192)
        int ph = f >> 3, k0 = f & 7;
        int ct = ph / 3, p = ph - ct * 3;
        int n = p * 128 + ct * 16 + (l & 15);
        float v;
        if (k0 < 4) v = gWih[(k0 * 32 + (l >> 4) * 8 + j) * 384 + n];
        else        v = gWhh[((k0 - 4) * 32 + (l >> 4) * 8 + j) * 384 + n];
        W2p[id] = f2bs(v);
    }
}

// ---------------------------------------------------------------------------
// High-occupancy neighbor gather: one wave per node, 8x unrolled.
// ---------------------------------------------------------------------------
__global__ __launch_bounds__(256) void k_gather(
    const bf16* __restrict__ hin, bf16* __restrict__ hagg,
    const int* __restrict__ offs, const int* __restrict__ srcs)
{
    int w = threadIdx.x >> 6, l = threadIdx.x & 63;
    int n = blockIdx.x * 4 + w;
    const ushort* hinu = (const ushort*)hin;
    int j0 = offs[n], j1 = offs[n + 1];
    j0 = j0 < 0 ? 0 : (j0 > N_EDGES ? N_EDGES : j0);
    j1 = j1 < j0 ? j0 : (j1 > N_EDGES ? N_EDGES : j1);

    float lo[8], hi8[8];
#pragma unroll
    for (int i = 0; i < 8; i++) { lo[i] = 0.f; hi8[i] = 0.f; }

    int j = j0;
    for (; j + 7 < j1; j += 8) {
        int ss[8];
        uint vv[8];
#pragma unroll
        for (int i = 0; i < 8; i++) {
            int s = srcs[j + i];
            ss[i] = s < 0 ? 0 : (s >= N_NODES ? N_NODES - 1 : s);
        }
#pragma unroll
        for (int i = 0; i < 8; i++)
            vv[i] = *(const uint*)(hinu + (size_t)ss[i] * D + l * 2);
#pragma unroll
        for (int i = 0; i < 8; i++) {
            lo[i] += __uint_as_float(vv[i] << 16);
            hi8[i] += __uint_as_float(vv[i] & 0xffff0000u);
        }
    }
    for (; j < j1; j++) {
        int s = srcs[j];
        s = s < 0 ? 0 : (s >= N_NODES ? N_NODES - 1 : s);
        uint v = *(const uint*)(hinu + (size_t)s * D + l * 2);
        lo[0] += __uint_as_float(v << 16);
        hi8[0] += __uint_as_float(v & 0xffff0000u);
    }
    float a0 = ((lo[0] + lo[1]) + (lo[2] + lo[3])) + ((lo[4] + lo[5]) + (lo[6] + lo[7]));
    float a1 = ((hi8[0] + hi8[1]) + (hi8[2] + hi8[3])) + ((hi8[4] + hi8[5]) + (hi8[6] + hi8[7]));
    uint ap = ((uint)(ushort)f2bs(a1) << 16) | (ushort)f2bs(a0);
    *(uint*)((ushort*)hagg + (size_t)n * D + l * 2) = ap;
}

// ---------------------------------------------------------------------------
// PERSISTENT SAGE linear: m = relu([agg|h] @ W1 + b_l).
// 256 blocks x 512 thr (8 waves = 2 rg x 4 cg).  Full W1 (64 KB) staged in
// LDS ONCE per block; block loops over row tiles (stride 256, ~3 tiles) with
// register double-buffered A-fragments.
// __launch_bounds__(512, 1): R7 evidence shows hipcc treats the 2nd arg as
// min BLOCKS/CU (CUDA-style): (512,2) -> 4 waves/EU -> 128-VGPR cap -> spill.
// (512,1) -> 1 block/CU -> 2 waves/EU -> 256-VGPR cap under either semantics;
// demand ~170 fits, no spill.
// ---------------------------------------------------------------------------
#define SAGE_LOAD(AF_A, AF_B, TIL)                                              \
{                                                                               \
    int bse_ = (TIL) * 64;                                                      \
    int ra_ = bse_ + rg * 32 + (l & 15);                                        \
    int rb_ = ra_ + 16;                                                         \
    int rca_ = ra_ < N_NODES ? ra_ : N_NODES - 1;                               \
    int rcb_ = rb_ < N_NODES ? rb_ : N_NODES - 1;                               \
    _Pragma("unroll")                                                           \
    for (int k0 = 0; k0 < 4; k0++) {                                            \
        AF_A[k0]     = *(const short8*)(aggu + (size_t)rca_ * D + k0 * 32 + koff);\
        AF_B[k0]     = *(const short8*)(aggu + (size_t)rcb_ * D + k0 * 32 + koff);\
        AF_A[4 + k0] = *(const short8*)(hu + (size_t)rca_ * D + k0 * 32 + koff);\
        AF_B[4 + k0] = *(const short8*)(hu + (size_t)rcb_ * D + k0 * 32 + koff);\
    }                                                                           \
}

#define SAGE_TILE(AF_A, AF_B, TIL)                                              \
{                                                                               \
    int bse_ = (TIL) * 64;                                                      \
    _Pragma("unroll")                                                           \
    for (int cti = 0; cti < 2; cti++) {                                         \
        int ct_ = cg * 2 + cti;                                                 \
        float4v accA = {0.f, 0.f, 0.f, 0.f};                                    \
        float4v accB = {0.f, 0.f, 0.f, 0.f};                                    \
        _Pragma("unroll")                                                       \
        for (int k0 = 0; k0 < 8; k0++) {                                        \
            short8 bw = *(const short8*)&w1s[(ct_ * 8 + k0) * 512 + l * 8];     \
            accA = __builtin_amdgcn_mfma_f32_16x16x32_bf16(AF_A[k0], bw, accA, 0, 0, 0);\
            accB = __builtin_amdgcn_mfma_f32_16x16x32_bf16(AF_B[k0], bw, accB, 0, 0, 0);\
        }                                                                       \
        float bb = bl[ct_ * 16 + (l & 15)];                                     \
        _Pragma("unroll")                                                       \
        for (int i = 0; i < 4; i++) {                                           \
            float vA = accA[i] + bb;                                            \
            float vB = accB[i] + bb;                                            \
            int ga = bse_ + crowA + i;                                          \
            int gb = bse_ + crowB + i;                                          \
            if (ga < N_NODES) mo[(size_t)ga * D + ct_ * 16 + (l & 15)] = (ushort)f2bs(vA > 0.f ? vA : 0.f);\
            if (gb < N_NODES) mo[(size_t)gb * D + ct_ * 16 + (l & 15)] = (ushort)f2bs(vB > 0.f ? vB : 0.f);\
        }                                                                       \
    }                                                                           \
}

__global__ __launch_bounds__(512, 1) void k_sage1(
    const bf16* __restrict__ hagg, const bf16* __restrict__ hin,
    const short* __restrict__ W1p, const float* __restrict__ bl,
    bf16* __restrict__ mout)
{
    __shared__ short8 w1v[4096];    // 64 KB: full W1, frag-ordered
    int t = threadIdx.x;
    int w = t >> 6, l = t & 63;
    int rg = w >> 2, cg = w & 3;
    int koff = (l >> 4) * 8;
    int crowA = rg * 32 + (l >> 4) * 4;
    int crowB = crowA + 16;
    const ushort* aggu = (const ushort*)hagg;
    const ushort* hu = (const ushort*)hin;
    ushort* mo = (ushort*)mout;
    const short* w1s = (const short*)w1v;

    short8 A0a[8], A0b[8], A1a[8], A1b[8];
    int t0 = blockIdx.x;
    SAGE_LOAD(A0a, A0b, t0);

    {
        const short8* src = (const short8*)W1p;
#pragma unroll
        for (int i = 0; i < 8; i++)
            w1v[i * 512 + t] = src[i * 512 + t];
    }
    __syncthreads();

    while (true) {
        int t1 = t0 + 256;
        if (t1 < NT64) { SAGE_LOAD(A1a, A1b, t1); SAGE_TILE(A0a, A0b, t0); }
        else { SAGE_TILE(A0a, A0b, t0); break; }
        int t2 = t1 + 256;
        if (t2 < NT64) { SAGE_LOAD(A0a, A0b, t2); SAGE_TILE(A1a, A1b, t1); }
        else { SAGE_TILE(A1a, A1b, t1); break; }
        t0 = t2;
    }
}

// ---------------------------------------------------------------------------
// PERSISTENT GRU: hout = GRU(m, h).  Col-half blocks (64 output cols):
// merged [Wih;Whh] half = 96 KB staged in LDS once; 128 blocks per half
// (grid 256, 1 block/CU, 8 waves).  Each wave owns (32 rows x 1 ct);
// loops over row tiles (stride 128, ~6 tiles) with A double-buffering.
// __launch_bounds__(512, 1): 256-VGPR cap (see k_sage1 note) — fixes the
// R6/R7 spill (VGPR=128, ~80 MB scratch each way, MfmaUtil 4.5%).
// ---------------------------------------------------------------------------
#define GRU_LOAD(AM_A, AH_A, AM_B, AH_B, TIL)                                   \
{                                                                               \
    int bse_ = (TIL) * 64;                                                      \
    int ra_ = bse_ + rg * 32 + (l & 15);                                        \
    int rb_ = ra_ + 16;                                                         \
    int rca_ = ra_ < N_NODES ? ra_ : N_NODES - 1;                               \
    int rcb_ = rb_ < N_NODES ? rb_ : N_NODES - 1;                               \
    _Pragma("unroll")                                                           \
    for (int k0 = 0; k0 < 4; k0++) {                                            \
        AM_A[k0] = *(const short8*)(mu + (size_t)rca_ * D + k0 * 32 + koff);    \
        AM_B[k0] = *(const short8*)(mu + (size_t)rcb_ * D + k0 * 32 + koff);    \
        AH_A[k0] = *(const short8*)(hu + (size_t)rca_ * D + k0 * 32 + koff);    \
        AH_B[k0] = *(const short8*)(hu + (size_t)rcb_ * D + k0 * 32 + koff);    \
    }                                                                           \
}

#define GRU_TILE(AM_A, AH_A, AM_B, AH_B, TIL)                                   \
{                                                                               \
    int bse_ = (TIL) * 64;                                                      \
    float h0A[4], h0B[4];                                                       \
    _Pragma("unroll")                                                           \
    for (int i = 0; i < 4; i++) {                                               \
        int ra_ = bse_ + crowA + i; ra_ = ra_ < N_NODES ? ra_ : N_NODES - 1;    \
        int rb_ = bse_ + crowB + i; rb_ = rb_ < N_NODES ? rb_ : N_NODES - 1;    \
        h0A[i] = bs2f((short)hu[(size_t)ra_ * D + c]);                          \
        h0B[i] = bs2f((short)hu[(size_t)rb_ * D + c]);                          \
    }                                                                           \
    float4v r0A = {0.f,0.f,0.f,0.f}, r0B = {0.f,0.f,0.f,0.f};                   \
    float4v z0A = {0.f,0.f,0.f,0.f}, z0B = {0.f,0.f,0.f,0.f};                   \
    float4v niA = {0.f,0.f,0.f,0.f}, niB = {0.f,0.f,0.f,0.f};                   \
    float4v nhA = {0.f,0.f,0.f,0.f}, nhB = {0.f,0.f,0.f,0.f};                   \
    _Pragma("unroll")                                                           \
    for (int k0 = 0; k0 < 4; k0++) {                                            \
        short8 bri = *(const short8*)&w2s[((cw*3+0)*8 + k0) * 512 + l * 8];     \
        short8 brh = *(const short8*)&w2s[((cw*3+0)*8 + 4 + k0) * 512 + l * 8]; \
        r0A = __builtin_amdgcn_mfma_f32_16x16x32_bf16(AM_A[k0], bri, r0A,0,0,0);\
        r0B = __builtin_amdgcn_mfma_f32_16x16x32_bf16(AM_B[k0], bri, r0B,0,0,0);\
        r0A = __builtin_amdgcn_mfma_f32_16x16x32_bf16(AH_A[k0], brh, r0A,0,0,0);\
        r0B = __builtin_amdgcn_mfma_f32_16x16x32_bf16(AH_B[k0], brh, r0B,0,0,0);\
        short8 bzi = *(const short8*)&w2s[((cw*3+1)*8 + k0) * 512 + l * 8];     \
        short8 bzh = *(const short8*)&w2s[((cw*3+1)*8 + 4 + k0) * 512 + l * 8]; \
        z0A = __builtin_amdgcn_mfma_f32_16x16x32_bf16(AM_A[k0], bzi, z0A,0,0,0);\
        z0B = __builtin_amdgcn_mfma_f32_16x16x32_bf16(AM_B[k0], bzi, z0B,0,0,0);\
        z0A = __builtin_amdgcn_mfma_f32_16x16x32_bf16(AH_A[k0], bzh, z0A,0,0,0);\
        z0B = __builtin_amdgcn_mfma_f32_16x16x32_bf16(AH_B[k0], bzh, z0B,0,0,0);\
        short8 bni = *(const short8*)&w2s[((cw*3+2)*8 + k0) * 512 + l * 8];     \
        short8 bnh = *(const short8*)&w2s[((cw*3+2)*8 + 4 + k0) * 512 + l * 8]; \
        niA = __builtin_amdgcn_mfma_f32_16x16x32_bf16(AM_A[k0], bni, niA,0,0,0);\
        niB = __builtin_amdgcn_mfma_f32_16x16x32_bf16(AM_B[k0], bni, niB,0,0,0);\
        nhA = __builtin_amdgcn_mfma_f32_16x16x32_bf16(AH_A[k0], bnh, nhA,0,0,0);\
        nhB = __builtin_amdgcn_mfma_f32_16x16x32_bf16(AH_B[k0], bnh, nhB,0,0,0);\
    }                                                                           \
    _Pragma("unroll")                                                           \
    for (int i = 0; i < 4; i++) {                                               \
        float rA = sigm(r0A[i] + bi_r + bh_r);                                  \
        float zA = sigm(z0A[i] + bi_z + bh_z);                                  \
        float nA = ftanh(niA[i] + bi_n + rA * (nhA[i] + bh_n));                 \
        int ga_ = bse_ + crowA + i;                                             \
        if (ga_ < N_NODES)                                                      \
            ho[(size_t)ga_ * D + c] = (ushort)f2bs((1.f - zA) * nA + zA * h0A[i]);\
        float rB = sigm(r0B[i] + bi_r + bh_r);                                  \
        float zB = sigm(z0B[i] + bi_z + bh_z);                                  \
        float nB = ftanh(niB[i] + bi_n + rB * (nhB[i] + bh_n));                 \
        int gb_ = bse_ + crowB + i;                                             \
        if (gb_ < N_NODES)                                                      \
            ho[(size_t)gb_ * D + c] = (ushort)f2bs((1.f - zB) * nB + zB * h0B[i]);\
    }                                                                           \
}

__global__ __launch_bounds__(512, 1) void k_gru2(
    const bf16* __restrict__ m, const bf16* __restrict__ hin,
    const short* __restrict__ W2p,
    const float* __restrict__ bih, const float* __restrict__ bhh,
    bf16* __restrict__ hout)
{
    __shared__ short8 w2v[6144];    // 96 KB: one col-half of merged [Wih;Whh]
    int t = threadIdx.x;
    int ch = blockIdx.x & 1, blk = blockIdx.x >> 1;
    int w = t >> 6, l = t & 63;
    int rg = w >> 2, cw = w & 3;
    int ct = ch * 4 + cw;
    int c = ct * 16 + (l & 15);
    int koff = (l >> 4) * 8;
    int crowA = rg * 32 + (l >> 4) * 4;
    int crowB = crowA + 16;
    const ushort* mu = (const ushort*)m;
    const ushort* hu = (const ushort*)hin;
    ushort* ho = (ushort*)hout;
    const short* w2s = (const short*)w2v;

    short8 M0a[4], H0a[4], M0b[4], H0b[4];
    short8 M1a[4], H1a[4], M1b[4], H1b[4];
    int t0 = blk;
    GRU_LOAD(M0a, H0a, M0b, H0b, t0);

    {
        const short8* src = (const short8*)(W2p + 49152 * ch);
#pragma unroll
        for (int i = 0; i < 12; i++)
            w2v[i * 512 + t] = src[i * 512 + t];
    }

    float bi_r = bih[c],       bh_r = bhh[c];
    float bi_z = bih[128 + c], bh_z = bhh[128 + c];
    float bi_n = bih[256 + c], bh_n = bhh[256 + c];
    __syncthreads();

    while (true) {
        int t1 = t0 + 128;
        if (t1 < NT64) { GRU_LOAD(M1a, H1a, M1b, H1b, t1); GRU_TILE(M0a, H0a, M0b, H0b, t0); }
        else { GRU_TILE(M0a, H0a, M0b, H0b, t0); break; }
        int t2 = t1 + 128;
        if (t2 < NT64) { GRU_LOAD(M0a, H0a, M0b, H0b, t2); GRU_TILE(M1a, H1a, M1b, H1b, t1); }
        else { GRU_TILE(M1a, H1a, M1b, H1b, t1); break; }
        t0 = t2;
    }
}

// ---------------------------------------------------------------------------
// Merged Set2Set step: LSTM + pool, 2 graphs per block.
// ---------------------------------------------------------------------------
#define POOL_CAP 1024
#define LG2 2
__global__ __launch_bounds__(1024) void k_s2s(
    const float* __restrict__ Wih, const float* __restrict__ Whh,
    const float* __restrict__ bih, const float* __restrict__ bhh,
    const bf16* __restrict__ h, const int* __restrict__ gstart,
    float* __restrict__ qstar, float* __restrict__ hh, float* __restrict__ cc, int first)
{
    int g0 = blockIdx.x * LG2;
    int t = threadIdx.x;
    __shared__ float qs[LG2][2 * D];
    __shared__ float hs[LG2][D];
    __shared__ float part[2][LG2][512];
    __shared__ float hnew[LG2][D];
    __shared__ float e_lds[POOL_CAP];
    __shared__ float redM[16], redS[16];
    __shared__ float rpart[8][D];

    for (int i = t; i < LG2 * 2 * D; i += 1024) {
        int g = i / (2 * D), c = i % (2 * D);
        qs[g][c] = first ? 0.f : qstar[(size_t)(g0 + g) * 2 * D + c];
    }
    for (int i = t; i < LG2 * D; i += 1024) {
        int g = i / D, c = i % D;
        hs[g][c] = first ? 0.f : hh[(size_t)(g0 + g) * D + c];
    }
    __syncthreads();

    int c = t & 511, half = t >> 9;
    float a0 = half ? 0.f : (bih[c] + bhh[c]);
    float a1 = a0;
    int qb = half * 128;
#pragma unroll 4
    for (int i = 0; i < 128; i++) {
        int k = qb + i;
        float wv = Wih[(size_t)k * 512 + c];
        a0 += qs[0][k] * wv;
        a1 += qs[1][k] * wv;
    }
    int hb = half * 64;
#pragma unroll 4
    for (int i = 0; i < 64; i++) {
        int k = hb + i;
        float wv = Whh[(size_t)k * 512 + c];
        a0 += hs[0][k] * wv;
        a1 += hs[1][k] * wv;
    }
    part[half][0][c] = a0;
    part[half][1][c] = a1;
    __syncthreads();

    if (t < LG2 * D) {
        int g = t >> 7, tt = t & 127;
        float gi = part[0][g][tt] + part[1][g][tt];
        float gf = part[0][g][D + tt] + part[1][g][D + tt];
        float gg2 = part[0][g][2 * D + tt] + part[1][g][2 * D + tt];
        float go = part[0][g][3 * D + tt] + part[1][g][3 * D + tt];
        float c_old = first ? 0.f : cc[(size_t)(g0 + g) * D + tt];
        float cn = sigm(gf) * c_old + sigm(gi) * ftanh(gg2);
        float hn = sigm(go) * ftanh(cn);
        cc[(size_t)(g0 + g) * D + tt] = cn;
        hh[(size_t)(g0 + g) * D + tt] = hn;
        qstar[(size_t)(g0 + g) * 2 * D + tt] = hn;
        hnew[g][tt] = hn;
    }
    __syncthreads();

    int w = t >> 6, l = t & 63;
    int dim = t & 127, h8 = t >> 7;
    const ushort* hu = (const ushort*)h;

    for (int gg = 0; gg < LG2; gg++) {
        int g = g0 + gg;
        int s0 = gstart[g], s1 = gstart[g + 1];
        s0 = s0 < 0 ? 0 : (s0 > N_NODES ? N_NODES : s0);
        s1 = s1 < s0 ? s0 : (s1 > N_NODES ? N_NODES : s1);
        int cnt = s1 - s0;

        float hq0 = hnew[gg][l];
        float hq1 = hnew[gg][64 + l];
        float m_run = -INFINITY, s_run = 0.f, racc = 0.f;

        for (int c0 = 0; c0 < cnt; c0 += POOL_CAP) {
            int clen = cnt - c0; if (clen > POOL_CAP) clen = POOL_CAP;

            for (int i = w; i < clen; i += 16) {
                int n = s0 + c0 + i;
                float v = bs2f((short)hu[(size_t)n * D + l]) * hq0
                        + bs2f((short)hu[(size_t)n * D + 64 + l]) * hq1;
#pragma unroll
                for (int off = 32; off > 0; off >>= 1) v += __shfl_down(v, off);
                if (l == 0) e_lds[i] = v;
            }
            __syncthreads();

            float m2 = -INFINITY;
            for (int i = t; i < clen; i += 1024) m2 = fmaxf(m2, e_lds[i]);
#pragma unroll
            for (int off = 32; off > 0; off >>= 1) m2 = fmaxf(m2, __shfl_down(m2, off));
            if (l == 0) redM[w] = m2;
            __syncthreads();
            m2 = -INFINITY;
#pragma unroll
            for (int i = 0; i < 16; i++) m2 = fmaxf(m2, redM[i]);
            float m_new = fmaxf(m_run, m2);
            float scale = (m_run == -INFINITY) ? 0.f : __expf(m_run - m_new);
            s_run *= scale;
            racc *= scale;
            __syncthreads();

            float s = 0.f;
            for (int i = t; i < clen; i += 1024) {
                float wv = __expf(e_lds[i] - m_new);
                e_lds[i] = wv;
                s += wv;
            }
#pragma unroll
            for (int off = 32; off > 0; off >>= 1) s += __shfl_down(s, off);
            if (l == 0) redS[w] = s;
            __syncthreads();
#pragma unroll
            for (int i = 0; i < 16; i++) s_run += redS[i];

            for (int i = h8; i < clen; i += 8)
                racc += e_lds[i] * bs2f((short)hu[(size_t)(s0 + c0 + i) * D + dim]);
            m_run = m_new;
            __syncthreads();
        }

        rpart[h8][dim] = racc;
        __syncthreads();
        if (t < D) {
            float inv = 1.f / (s_run + 1e-16f);
            float r = 0.f;
#pragma unroll
            for (int i = 0; i < 8; i++) r += rpart[i][t];
            qstar[(size_t)g * 2 * D + D + t] = r * inv;
        }
        __syncthreads();
    }
}

// ---------------------------------------------------------------------------
// Head: y = leaky(q_star@W_lin + b_lin) @ W_fin + b_fin   -> fp32 out
// ---------------------------------------------------------------------------
__global__ __launch_bounds__(128) void k_final(
    const float* __restrict__ qstar, const float* __restrict__ Wlin, const float* __restrict__ blin,
    const float* __restrict__ Wfin, const float* __restrict__ bfin, float* __restrict__ outp)
{
    int g = blockIdx.x, t = threadIdx.x;
    __shared__ float qs[2 * D], ts[D];
    qs[t] = qstar[(size_t)g * 2 * D + t];
    qs[D + t] = qstar[(size_t)g * 2 * D + D + t];
    __syncthreads();

    float acc = blin[t];
    for (int k = 0; k < 2 * D; k++) acc += qs[k] * Wlin[(size_t)k * D + t];
    ts[t] = leaky(acc);
    __syncthreads();

    if (t < L_DIM) {
        float a2 = bfin[t];
        for (int k = 0; k < D; k++) a2 += ts[k] * Wfin[(size_t)k * L_DIM + t];
        outp[(size_t)g * L_DIM + t] = a2;
    }
}

// ---------------------------------------------------------------------------
extern "C" void kernel_launch(void* const* d_in, const int* in_sizes, int n_in,
                              void* d_out, int out_size, void* d_ws, size_t ws_size,
                              hipStream_t stream)
{
    const float* x      = (const float*)d_in[0];
    const int*   ei     = (const int*)d_in[1];
    const int*   batch  = (const int*)d_in[3];
    const float* Wemb   = (const float*)d_in[4];
    const float* bemb   = (const float*)d_in[5];
    const float* Wfirst = (const float*)d_in[6];
    const float* bfirst = (const float*)d_in[7];
    const float* Wl     = (const float*)d_in[8];
    const float* bl     = (const float*)d_in[9];
    const float* Wr     = (const float*)d_in[10];
    const float* gWih   = (const float*)d_in[11];
    const float* gWhh   = (const float*)d_in[12];
    const float* gbih   = (const float*)d_in[13];
    const float* gbhh   = (const float*)d_in[14];
    const float* lWih   = (const float*)d_in[15];
    const float* lWhh   = (const float*)d_in[16];
    const float* lbih   = (const float*)d_in[17];
    const float* lbhh   = (const float*)d_in[18];
    const float* Wlin   = (const float*)d_in[19];
    const float* blin   = (const float*)d_in[20];
    const float* Wfin   = (const float*)d_in[21];
    const float* bfin   = (const float*)d_in[22];
    float* outp = (float*)d_out;

    // ---- workspace carve (256B-aligned slabs), ~46 MB ----
    size_t o = 0;
    char* base = (char*)d_ws;
    auto carve = [&](size_t bytes) { void* p = base + o; o += (bytes + 255) & ~(size_t)255; return p; };
    bf16*  h0     = (bf16*)carve((size_t)N_NODES * D * sizeof(bf16));
    bf16*  h1     = (bf16*)carve((size_t)N_NODES * D * sizeof(bf16));
    bf16*  mbuf   = (bf16*)carve((size_t)N_NODES * D * sizeof(bf16));
    int*   offs   = (int*)carve((size_t)SCAN_N * sizeof(int));
    int*   srcs   = (int*)carve((size_t)N_EDGES * sizeof(int));
    int*   bcnt   = (int*)carve((size_t)(NBUCK + 1) * sizeof(int));
    int*   bcur   = (int*)carve((size_t)NBUCK * sizeof(int));
    uint*  ebuf   = (uint*)carve((size_t)N_EDGES * sizeof(uint));
    float* hh     = (float*)carve((size_t)N_GRAPHS * D * sizeof(float));
    float* cc     = (float*)carve((size_t)N_GRAPHS * D * sizeof(float));
    float* qstar  = (float*)carve((size_t)N_GRAPHS * 2 * D * sizeof(float));
    int*   gstart = (int*)carve((size_t)(N_GRAPHS + 1) * sizeof(int));
    short* W1p    = (short*)carve((size_t)256 * 128 * sizeof(short));
    short* W2p    = (short*)carve((size_t)256 * 384 * sizeof(short));
    size_t need = o;

    if (ws_size < need) {
        k_signal<<<(out_size + 255) / 256, 256, 0, stream>>>(outp, out_size);
        return;
    }

    // node MLP -> h0
    k_embed<<<N_NODES / NPE, 128, 0, stream>>>(x, Wemb, bemb, Wfirst, bfirst, h0);

    // all weight packing (32768 W1 + 98304 W2 threads)
    k_pack_all<<<(32768 + 98304) / 256, 256, 0, stream>>>(Wl, Wr, gWih, gWhh, W1p, W2p);

    // bucketed CSR build (LDS-aggregated placement)
    hipMemsetAsync(bcnt, 0, (size_t)((char*)ebuf - (char*)bcnt), stream);
    k_bcount<<<128, 256, 0, stream>>>(ei, bcnt);
    k_bscan<<<1, 64, 0, stream>>>(bcnt);
    k_bfill2<<<(N_EDGES + EPB - 1) / EPB, BFT, 0, stream>>>(ei, bcnt, bcur, ebuf);
    k_csr<<<NBUCK, 256, 0, stream>>>(bcnt, ebuf, offs, srcs);

    // graph segment starts
    k_gstart<<<(N_GRAPHS + 1 + 255) / 256, 256, 0, stream>>>(batch, gstart);

    // 3 message-passing steps: gather -> SAGE linear (persistent) -> GRU (persistent)
    bf16* hc = h0; bf16* hn = h1;
    for (int s = 0; s < 3; s++) {
        k_gather<<<N_NODES / 4, 256, 0, stream>>>(hc, hn, offs, srcs);
        k_sage1<<<256, 512, 0, stream>>>(hn, hc, W1p, bl, mbuf);
        k_gru2<<<256, 512, 0, stream>>>(mbuf, hc, W2p, gbih, gbhh, hn);
        bf16* tmp = hc; hc = hn; hn = tmp;
    }

    // Set2Set: merged LSTM+pool, 2 graphs/block
    for (int s = 0; s < 3; s++) {
        k_s2s<<<N_GRAPHS / LG2, 1024, 0, stream>>>(lWih, lWhh, lbih, lbhh,
                                                   hc, gstart, qstar, hh, cc, s == 0);
    }

    k_final<<<N_GRAPHS, 128, 0, stream>>>(qstar, Wlin, blin, Wfin, bfin, outp);
}

// Round 9
// 561.324 us; speedup vs baseline: 1.2884x; 1.2884x over previous
//
#include <hip/hip_runtime.h>
#include <hip/hip_bf16.h>
#include <math.h>

#define N_NODES 50000
#define N_EDGES 800000
#define N_GRAPHS 512
#define F_IN 16
#define E_DIM 64
#define D 128
#define L_DIM 64
#define NEG_SLOPE 0.01f

#define SCAN_N (N_NODES + 1)                  // 50001
#define NBUCK ((N_NODES + 127) >> 7)          // 391 buckets of 128 nodes
#define EPT 4
#define BFT 1024
#define EPB (BFT * EPT)                       // 4096 edges per block
#define NT64 ((N_NODES + 63) / 64)            // 782 row tiles of 64

typedef __hip_bfloat16 bf16;
typedef unsigned int uint;
typedef unsigned short ushort;
typedef __attribute__((ext_vector_type(8))) short short8;
typedef __attribute__((ext_vector_type(4))) float float4v;

__device__ __forceinline__ float b2f(bf16 v) { return __bfloat162float(v); }
__device__ __forceinline__ bf16  f2b(float v) { return __float2bfloat16(v); }
__device__ __forceinline__ short f2bs(float f) { bf16 b = __float2bfloat16(f); return *reinterpret_cast<short*>(&b); }
__device__ __forceinline__ float bs2f(short s) { return __uint_as_float(((uint)(ushort)s) << 16); }
__device__ __forceinline__ float leaky(float v) { return v > 0.f ? v : NEG_SLOPE * v; }

// fast transcendentals: v_exp_f32 / v_rcp_f32 based.
__device__ __forceinline__ float frcp(float x) { return __builtin_amdgcn_rcpf(x); }
__device__ __forceinline__ float sigm(float v) { return frcp(1.f + __expf(-v)); }
__device__ __forceinline__ float ftanh(float v)
{
    v = fminf(15.f, fmaxf(-15.f, v));
    float a = __expf(2.f * v);
    return (a - 1.f) * frcp(a + 1.f);
}

// ---------------------------------------------------------------------------
__global__ __launch_bounds__(256) void k_signal(float* outp, int n)
{
    int i = blockIdx.x * 256 + threadIdx.x;
    if (i < n) outp[i] = 1.0f;
}

// ---------------------------------------------------------------------------
// h0 = leaky(leaky(x@W_emb + b_emb) @ W_first + b_first)  -> bf16
// ---------------------------------------------------------------------------
#define NPE 16
__global__ __launch_bounds__(128) void k_embed(
    const float* __restrict__ x, const float* __restrict__ Wemb, const float* __restrict__ bemb,
    const float* __restrict__ Wfirst, const float* __restrict__ bfirst, bf16* __restrict__ out)
{
    __shared__ float xs[NPE][F_IN];
    __shared__ float ys[NPE][E_DIM];
    int t = threadIdx.x;
    int base = blockIdx.x * NPE;

    for (int i = t; i < NPE * F_IN; i += 128)
        xs[i / F_IN][i % F_IN] = x[(size_t)base * F_IN + i];
    __syncthreads();

    if (t < E_DIM) {
        float acc[NPE];
#pragma unroll
        for (int nn = 0; nn < NPE; nn++) acc[nn] = 0.f;
        for (int k = 0; k < F_IN; k++) {
            float w = Wemb[k * E_DIM + t];
#pragma unroll
            for (int nn = 0; nn < NPE; nn++) acc[nn] += xs[nn][k] * w;
        }
        float bb = bemb[t];
#pragma unroll
        for (int nn = 0; nn < NPE; nn++) ys[nn][t] = leaky(acc[nn] + bb);
    }
    __syncthreads();

    {
        float acc[NPE];
#pragma unroll
        for (int nn = 0; nn < NPE; nn++) acc[nn] = 0.f;
        for (int k = 0; k < E_DIM; k++) {
            float w = Wfirst[k * D + t];
#pragma unroll
            for (int nn = 0; nn < NPE; nn++) acc[nn] += ys[nn][k] * w;
        }
        float bb = bfirst[t];
#pragma unroll
        for (int nn = 0; nn < NPE; nn++)
            out[(size_t)(base + nn) * D + t] = f2b(leaky(acc[nn] + bb));
    }
}

// ---------------------------------------------------------------------------
// Bucketed CSR build.
// ---------------------------------------------------------------------------
__global__ __launch_bounds__(256) void k_bcount(const int* __restrict__ ei, int* __restrict__ bcnt)
{
    __shared__ int lc[NBUCK];
    for (int i = threadIdx.x; i < NBUCK; i += 256) lc[i] = 0;
    __syncthreads();
    int stride = gridDim.x * 256;
    for (int e = blockIdx.x * 256 + threadIdx.x; e < N_EDGES; e += stride) {
        int d = ei[N_EDGES + e];
        d = d < 0 ? 0 : (d >= N_NODES ? N_NODES - 1 : d);
        atomicAdd(&lc[d >> 7], 1);
    }
    __syncthreads();
    for (int i = threadIdx.x; i < NBUCK; i += 256)
        if (lc[i]) atomicAdd(&bcnt[i + 1], lc[i]);
}

__global__ void k_bscan(int* __restrict__ bcnt)
{
    if (threadIdx.x == 0 && blockIdx.x == 0) {
        int run = 0;
        for (int i = 0; i <= NBUCK; i++) { run += bcnt[i]; bcnt[i] = run; }
    }
}

__global__ __launch_bounds__(BFT) void k_bfill2(
    const int* __restrict__ ei, const int* __restrict__ bstart,
    int* __restrict__ bcur, uint* __restrict__ ebuf)
{
    __shared__ int lcnt[NBUCK];
    __shared__ int lbase[NBUCK];
    int t = threadIdx.x;
    int e0 = blockIdx.x * EPB;

    for (int i = t; i < NBUCK; i += BFT) lcnt[i] = 0;
    __syncthreads();

    uint pk[EPT];
    int bb[EPT];
#pragma unroll
    for (int q = 0; q < EPT; q++) {
        int e = e0 + q * BFT + t;          // coalesced reads
        bb[q] = -1;
        if (e < N_EDGES) {
            int s = ei[e];
            int d = ei[N_EDGES + e];
            s = s < 0 ? 0 : (s >= N_NODES ? N_NODES - 1 : s);
            d = d < 0 ? 0 : (d >= N_NODES ? N_NODES - 1 : d);
            bb[q] = d >> 7;
            pk[q] = ((uint)(d & 127) << 16) | (uint)s;
            atomicAdd(&lcnt[bb[q]], 1);    // LDS atomic (fast)
        }
    }
    __syncthreads();

    for (int i = t; i < NBUCK; i += BFT) {
        int cv = lcnt[i];
        lbase[i] = cv > 0 ? atomicAdd(&bcur[i], cv) : 0;
    }
    __syncthreads();
    for (int i = t; i < NBUCK; i += BFT) lcnt[i] = 0;   // reuse as cursor
    __syncthreads();

#pragma unroll
    for (int q = 0; q < EPT; q++) {
        if (bb[q] >= 0) {
            int pos = lbase[bb[q]] + atomicAdd(&lcnt[bb[q]], 1);
            int slot = bstart[bb[q]] + pos;
            if (slot >= 0 && slot < N_EDGES) ebuf[slot] = pk[q];
        }
    }
}

__global__ __launch_bounds__(256) void k_csr(
    const int* __restrict__ bstart, const uint* __restrict__ ebuf,
    int* __restrict__ offs, int* __restrict__ srcs)
{
    __shared__ int cnt[128];
    __shared__ int loffs[129];
    int b = blockIdx.x, t = threadIdx.x;
    int e0 = bstart[b], e1 = bstart[b + 1];
    if (t < 128) cnt[t] = 0;
    __syncthreads();
    for (int j = e0 + t; j < e1; j += 256)
        atomicAdd(&cnt[(ebuf[j] >> 16) & 127], 1);
    __syncthreads();
    if (t == 0) {
        int run = 0;
        for (int i = 0; i < 128; i++) { loffs[i] = run; run += cnt[i]; }
        loffs[128] = run;
    }
    __syncthreads();
    int n0 = b << 7;
    if (t < 128) {
        int n = n0 + t;
        if (n <= N_NODES) offs[n] = e0 + loffs[t];
        cnt[t] = 0;
    }
    __syncthreads();
    for (int j = e0 + t; j < e1; j += 256) {
        uint pk = ebuf[j];
        int dl = (pk >> 16) & 127;
        int rank = atomicAdd(&cnt[dl], 1);
        int slot = e0 + loffs[dl] + rank;
        if (slot >= 0 && slot < N_EDGES) srcs[slot] = (int)(pk & 0xffffu);
    }
}

// ---------------------------------------------------------------------------
__global__ __launch_bounds__(256) void k_gstart(const int* __restrict__ batch, int* __restrict__ gstart)
{
    int g = blockIdx.x * 256 + threadIdx.x;
    if (g > N_GRAPHS) return;
    int lo = 0, hi = N_NODES;
    while (lo < hi) {
        int mid = (lo + hi) >> 1;
        if (batch[mid] < g) lo = mid + 1; else hi = mid;
    }
    gstart[g] = lo;
}

// ---------------------------------------------------------------------------
// Weight packing.
//   W1p : frag f = ct*8 + k0, 512 shorts/frag (k = kb*32+(l>>4)*8+j, n = ct*16+(l&15))
//   W2p : merged [Wih;Whh], frag f = ph*8 + k0; ph = ct*3 + p; k0<4 from Wih
//         (k = k0*32+...), k0>=4 from Whh (k=(k0-4)*32+...); n = p*128+ct*16+(l&15)
// ---------------------------------------------------------------------------
__global__ __launch_bounds__(256) void k_pack_all(
    const float* __restrict__ Wl, const float* __restrict__ Wr,
    const float* __restrict__ gWih, const float* __restrict__ gWhh,
    short* __restrict__ W1p, short* __restrict__ W2p)
{
    int tid = blockIdx.x * 256 + threadIdx.x;     // 131072 total
    if (tid < 32768) {
        int j = tid & 7, l = (tid >> 3) & 63, frag = tid >> 9;
        int nb = frag >> 3, kb = frag & 7;        // frag = ct*8 + k0
        int k = kb * 32 + ((l >> 4) * 8) + j;
        int n = nb * 16 + (l & 15);
        float v = (k < 128) ? Wl[k * D + n] : Wr[(k - 128) * D + n];
        W1p[tid] = f2bs(v);
    } else {
        int id = tid - 32768;                     // [0, 98304)
        int j = id & 7, l = (id >> 3) & 63, f = id >> 9;   // f in [0,192)
        int ph = f >> 3, k0 = f & 7;
        int ct = ph / 3, p = ph - ct * 3;
        int n = p * 128 + ct * 16 + (l & 15);
        float v;
        if (k0 < 4) v = gWih[(k0 * 32 + (l >> 4) * 8 + j) * 384 + n];
        else        v = gWhh[((k0 - 4) * 32 + (l >> 4) * 8 + j) * 384 + n];
        W2p[id] = f2bs(v);
    }
}

// ---------------------------------------------------------------------------
// High-occupancy neighbor gather: one wave per node, 8x unrolled.
// ---------------------------------------------------------------------------
__global__ __launch_bounds__(256) void k_gather(
    const bf16* __restrict__ hin, bf16* __restrict__ hagg,
    const int* __restrict__ offs, const int* __restrict__ srcs)
{
    int w = threadIdx.x >> 6, l = threadIdx.x & 63;
    int n = blockIdx.x * 4 + w;
    const ushort* hinu = (const ushort*)hin;
    int j0 = offs[n], j1 = offs[n + 1];
    j0 = j0 < 0 ? 0 : (j0 > N_EDGES ? N_EDGES : j0);
    j1 = j1 < j0 ? j0 : (j1 > N_EDGES ? N_EDGES : j1);

    float lo[8], hi8[8];
#pragma unroll
    for (int i = 0; i < 8; i++) { lo[i] = 0.f; hi8[i] = 0.f; }

    int j = j0;
    for (; j + 7 < j1; j += 8) {
        int ss[8];
        uint vv[8];
#pragma unroll
        for (int i = 0; i < 8; i++) {
            int s = srcs[j + i];
            ss[i] = s < 0 ? 0 : (s >= N_NODES ? N_NODES - 1 : s);
        }
#pragma unroll
        for (int i = 0; i < 8; i++)
            vv[i] = *(const uint*)(hinu + (size_t)ss[i] * D + l * 2);
#pragma unroll
        for (int i = 0; i < 8; i++) {
            lo[i] += __uint_as_float(vv[i] << 16);
            hi8[i] += __uint_as_float(vv[i] & 0xffff0000u);
        }
    }
    for (; j < j1; j++) {
        int s = srcs[j];
        s = s < 0 ? 0 : (s >= N_NODES ? N_NODES - 1 : s);
        uint v = *(const uint*)(hinu + (size_t)s * D + l * 2);
        lo[0] += __uint_as_float(v << 16);
        hi8[0] += __uint_as_float(v & 0xffff0000u);
    }
    float a0 = ((lo[0] + lo[1]) + (lo[2] + lo[3])) + ((lo[4] + lo[5]) + (lo[6] + lo[7]));
    float a1 = ((hi8[0] + hi8[1]) + (hi8[2] + hi8[3])) + ((hi8[4] + hi8[5]) + (hi8[6] + hi8[7]));
    uint ap = ((uint)(ushort)f2bs(a1) << 16) | (ushort)f2bs(a0);
    *(uint*)((ushort*)hagg + (size_t)n * D + l * 2) = ap;
}

// ---------------------------------------------------------------------------
// PERSISTENT SAGE linear: m = relu([agg|h] @ W1 + b_l).
// 256 blocks x 512 thr (8 waves = 2 rg x 4 cg).  Full W1 (64 KB) staged in
// LDS ONCE per block; block loops over row tiles (stride 256, ~3 tiles).
// SINGLE-buffered A-frags: hipcc hard-caps this kernel at 128 VGPRs
// (launch_bounds hints had zero effect R6-R8); double-buffering demanded
// ~210 and spilled ~80 MB to scratch.  Single-buffer demand ~90 — fits.
// ---------------------------------------------------------------------------
#define SAGE_LOAD(AF_A, AF_B, TIL)                                              \
{                                                                               \
    int bse_ = (TIL) * 64;                                                      \
    int ra_ = bse_ + rg * 32 + (l & 15);                                        \
    int rb_ = ra_ + 16;                                                         \
    int rca_ = ra_ < N_NODES ? ra_ : N_NODES - 1;                               \
    int rcb_ = rb_ < N_NODES ? rb_ : N_NODES - 1;                               \
    _Pragma("unroll")                                                           \
    for (int k0 = 0; k0 < 4; k0++) {                                            \
        AF_A[k0]     = *(const short8*)(aggu + (size_t)rca_ * D + k0 * 32 + koff);\
        AF_B[k0]     = *(const short8*)(aggu + (size_t)rcb_ * D + k0 * 32 + koff);\
        AF_A[4 + k0] = *(const short8*)(hu + (size_t)rca_ * D + k0 * 32 + koff);\
        AF_B[4 + k0] = *(const short8*)(hu + (size_t)rcb_ * D + k0 * 32 + koff);\
    }                                                                           \
}

#define SAGE_TILE(AF_A, AF_B, TIL)                                              \
{                                                                               \
    int bse_ = (TIL) * 64;                                                      \
    _Pragma("unroll")                                                           \
    for (int cti = 0; cti < 2; cti++) {                                         \
        int ct_ = cg * 2 + cti;                                                 \
        float4v accA = {0.f, 0.f, 0.f, 0.f};                                    \
        float4v accB = {0.f, 0.f, 0.f, 0.f};                                    \
        _Pragma("unroll")                                                       \
        for (int k0 = 0; k0 < 8; k0++) {                                        \
            short8 bw = *(const short8*)&w1s[(ct_ * 8 + k0) * 512 + l * 8];     \
            accA = __builtin_amdgcn_mfma_f32_16x16x32_bf16(AF_A[k0], bw, accA, 0, 0, 0);\
            accB = __builtin_amdgcn_mfma_f32_16x16x32_bf16(AF_B[k0], bw, accB, 0, 0, 0);\
        }                                                                       \
        float bb = bl[ct_ * 16 + (l & 15)];                                     \
        _Pragma("unroll")                                                       \
        for (int i = 0; i < 4; i++) {                                           \
            float vA = accA[i] + bb;                                            \
            float vB = accB[i] + bb;                                            \
            int ga = bse_ + crowA + i;                                          \
            int gb = bse_ + crowB + i;                                          \
            if (ga < N_NODES) mo[(size_t)ga * D + ct_ * 16 + (l & 15)] = (ushort)f2bs(vA > 0.f ? vA : 0.f);\
            if (gb < N_NODES) mo[(size_t)gb * D + ct_ * 16 + (l & 15)] = (ushort)f2bs(vB > 0.f ? vB : 0.f);\
        }                                                                       \
    }                                                                           \
}

__global__ __launch_bounds__(512) void k_sage1(
    const bf16* __restrict__ hagg, const bf16* __restrict__ hin,
    const short* __restrict__ W1p, const float* __restrict__ bl,
    bf16* __restrict__ mout)
{
    __shared__ short8 w1v[4096];    // 64 KB: full W1, frag-ordered
    int t = threadIdx.x;
    int w = t >> 6, l = t & 63;
    int rg = w >> 2, cg = w & 3;
    int koff = (l >> 4) * 8;
    int crowA = rg * 32 + (l >> 4) * 4;
    int crowB = crowA + 16;
    const ushort* aggu = (const ushort*)hagg;
    const ushort* hu = (const ushort*)hin;
    ushort* mo = (ushort*)mout;
    const short* w1s = (const short*)w1v;

    short8 A0a[8], A0b[8];
    int t0 = blockIdx.x;
    SAGE_LOAD(A0a, A0b, t0);            // first tile's loads overlap staging

    {
        const short8* src = (const short8*)W1p;
#pragma unroll
        for (int i = 0; i < 8; i++)
            w1v[i * 512 + t] = src[i * 512 + t];
    }
    __syncthreads();

    while (true) {
        SAGE_TILE(A0a, A0b, t0);
        t0 += 256;
        if (t0 >= NT64) break;
        SAGE_LOAD(A0a, A0b, t0);
    }
}

// ---------------------------------------------------------------------------
// PERSISTENT GRU: hout = GRU(m, h).  Col-half blocks (64 output cols):
// merged [Wih;Whh] half = 96 KB staged in LDS once; grid 256, 8 waves,
// each wave (32 rows x 1 ct), loops over row tiles (stride 128, ~6 tiles).
// SINGLE-buffered A-frags + two-phase gate computation (r/z accumulate ->
// scalarize -> n accumulate) keep peak VGPR demand ~115 < the 128 hard cap
// (R6-R8: double-buffer demanded ~210, spilled 80 MB scratch each way).
// h0 loads issue at tile start so the r/z MFMA phase hides their latency.
// ---------------------------------------------------------------------------
#define GRU_LOAD(AM_A, AH_A, AM_B, AH_B, TIL)                                   \
{                                                                               \
    int bse_ = (TIL) * 64;                                                      \
    int ra_ = bse_ + rg * 32 + (l & 15);                                        \
    int rb_ = ra_ + 16;                                                         \
    int rca_ = ra_ < N_NODES ? ra_ : N_NODES - 1;                               \
    int rcb_ = rb_ < N_NODES ? rb_ : N_NODES - 1;                               \
    _Pragma("unroll")                                                           \
    for (int k0 = 0; k0 < 4; k0++) {                                            \
        AM_A[k0] = *(const short8*)(mu + (size_t)rca_ * D + k0 * 32 + koff);    \
        AM_B[k0] = *(const short8*)(mu + (size_t)rcb_ * D + k0 * 32 + koff);    \
        AH_A[k0] = *(const short8*)(hu + (size_t)rca_ * D + k0 * 32 + koff);    \
        AH_B[k0] = *(const short8*)(hu + (size_t)rcb_ * D + k0 * 32 + koff);    \
    }                                                                           \
}

#define GRU_TILE(AM_A, AH_A, AM_B, AH_B, TIL)                                   \
{                                                                               \
    int bse_ = (TIL) * 64;                                                      \
    float h0A[4], h0B[4];                                                       \
    _Pragma("unroll")                                                           \
    for (int i = 0; i < 4; i++) {                                               \
        int ra_ = bse_ + crowA + i; ra_ = ra_ < N_NODES ? ra_ : N_NODES - 1;    \
        int rb_ = bse_ + crowB + i; rb_ = rb_ < N_NODES ? rb_ : N_NODES - 1;    \
        h0A[i] = bs2f((short)hu[(size_t)ra_ * D + c]);                          \
        h0B[i] = bs2f((short)hu[(size_t)rb_ * D + c]);                          \
    }                                                                           \
    /* phase 1: r and z gates */                                                \
    float rvA[4], rvB[4], zvA[4], zvB[4];                                       \
    {                                                                           \
        float4v r0A = {0.f,0.f,0.f,0.f}, r0B = {0.f,0.f,0.f,0.f};               \
        float4v z0A = {0.f,0.f,0.f,0.f}, z0B = {0.f,0.f,0.f,0.f};               \
        _Pragma("unroll")                                                       \
        for (int k0 = 0; k0 < 4; k0++) {                                        \
            short8 bri = *(const short8*)&w2s[((cw*3+0)*8 + k0) * 512 + l * 8]; \
            short8 brh = *(const short8*)&w2s[((cw*3+0)*8 + 4 + k0) * 512 + l * 8];\
            r0A = __builtin_amdgcn_mfma_f32_16x16x32_bf16(AM_A[k0], bri, r0A,0,0,0);\
            r0B = __builtin_amdgcn_mfma_f32_16x16x32_bf16(AM_B[k0], bri, r0B,0,0,0);\
            r0A = __builtin_amdgcn_mfma_f32_16x16x32_bf16(AH_A[k0], brh, r0A,0,0,0);\
            r0B = __builtin_amdgcn_mfma_f32_16x16x32_bf16(AH_B[k0], brh, r0B,0,0,0);\
            short8 bzi = *(const short8*)&w2s[((cw*3+1)*8 + k0) * 512 + l * 8]; \
            short8 bzh = *(const short8*)&w2s[((cw*3+1)*8 + 4 + k0) * 512 + l * 8];\
            z0A = __builtin_amdgcn_mfma_f32_16x16x32_bf16(AM_A[k0], bzi, z0A,0,0,0);\
            z0B = __builtin_amdgcn_mfma_f32_16x16x32_bf16(AM_B[k0], bzi, z0B,0,0,0);\
            z0A = __builtin_amdgcn_mfma_f32_16x16x32_bf16(AH_A[k0], bzh, z0A,0,0,0);\
            z0B = __builtin_amdgcn_mfma_f32_16x16x32_bf16(AH_B[k0], bzh, z0B,0,0,0);\
        }                                                                       \
        _Pragma("unroll")                                                       \
        for (int i = 0; i < 4; i++) {                                           \
            rvA[i] = sigm(r0A[i] + bi_r + bh_r);                                \
            rvB[i] = sigm(r0B[i] + bi_r + bh_r);                                \
            zvA[i] = sigm(z0A[i] + bi_z + bh_z);                                \
            zvB[i] = sigm(z0B[i] + bi_z + bh_z);                                \
        }                                                                       \
    }                                                                           \
    /* phase 2: n gate (ih and hh kept separate for the r* coupling) */         \
    {                                                                           \
        float4v niA = {0.f,0.f,0.f,0.f}, niB = {0.f,0.f,0.f,0.f};               \
        float4v nhA = {0.f,0.f,0.f,0.f}, nhB = {0.f,0.f,0.f,0.f};               \
        _Pragma("unroll")                                                       \
        for (int k0 = 0; k0 < 4; k0++) {                                        \
            short8 bni = *(const short8*)&w2s[((cw*3+2)*8 + k0) * 512 + l * 8]; \
            short8 bnh = *(const short8*)&w2s[((cw*3+2)*8 + 4 + k0) * 512 + l * 8];\
            niA = __builtin_amdgcn_mfma_f32_16x16x32_bf16(AM_A[k0], bni, niA,0,0,0);\
            niB = __builtin_amdgcn_mfma_f32_16x16x32_bf16(AM_B[k0], bni, niB,0,0,0);\
            nhA = __builtin_amdgcn_mfma_f32_16x16x32_bf16(AH_A[k0], bnh, nhA,0,0,0);\
            nhB = __builtin_amdgcn_mfma_f32_16x16x32_bf16(AH_B[k0], bnh, nhB,0,0,0);\
        }                                                                       \
        _Pragma("unroll")                                                       \
        for (int i = 0; i < 4; i++) {                                           \
            float nA = ftanh(niA[i] + bi_n + rvA[i] * (nhA[i] + bh_n));         \
            int ga_ = bse_ + crowA + i;                                         \
            if (ga_ < N_NODES)                                                  \
                ho[(size_t)ga_ * D + c] = (ushort)f2bs((1.f - zvA[i]) * nA + zvA[i] * h0A[i]);\
            float nB = ftanh(niB[i] + bi_n + rvB[i] * (nhB[i] + bh_n));         \
            int gb_ = bse_ + crowB + i;                                         \
            if (gb_ < N_NODES)                                                  \
                ho[(size_t)gb_ * D + c] = (ushort)f2bs((1.f - zvB[i]) * nB + zvB[i] * h0B[i]);\
        }                                                                       \
    }                                                                           \
}

__global__ __launch_bounds__(512) void k_gru2(
    const bf16* __restrict__ m, const bf16* __restrict__ hin,
    const short* __restrict__ W2p,
    const float* __restrict__ bih, const float* __restrict__ bhh,
    bf16* __restrict__ hout)
{
    __shared__ short8 w2v[6144];    // 96 KB: one col-half of merged [Wih;Whh]
    int t = threadIdx.x;
    int ch = blockIdx.x & 1, blk = blockIdx.x >> 1;
    int w = t >> 6, l = t & 63;
    int rg = w >> 2, cw = w & 3;
    int ct = ch * 4 + cw;
    int c = ct * 16 + (l & 15);
    int koff = (l >> 4) * 8;
    int crowA = rg * 32 + (l >> 4) * 4;
    int crowB = crowA + 16;
    const ushort* mu = (const ushort*)m;
    const ushort* hu = (const ushort*)hin;
    ushort* ho = (ushort*)hout;
    const short* w2s = (const short*)w2v;

    short8 M0a[4], H0a[4], M0b[4], H0b[4];
    int t0 = blk;
    GRU_LOAD(M0a, H0a, M0b, H0b, t0);   // first tile's loads overlap staging

    {
        const short8* src = (const short8*)(W2p + 49152 * ch);
#pragma unroll
        for (int i = 0; i < 12; i++)
            w2v[i * 512 + t] = src[i * 512 + t];
    }

    float bi_r = bih[c],       bh_r = bhh[c];
    float bi_z = bih[128 + c], bh_z = bhh[128 + c];
    float bi_n = bih[256 + c], bh_n = bhh[256 + c];
    __syncthreads();

    while (true) {
        GRU_TILE(M0a, H0a, M0b, H0b, t0);
        t0 += 128;
        if (t0 >= NT64) break;
        GRU_LOAD(M0a, H0a, M0b, H0b, t0);
    }
}

// ---------------------------------------------------------------------------
// Merged Set2Set step: LSTM + pool, 2 graphs per block.
// ---------------------------------------------------------------------------
#define POOL_CAP 1024
#define LG2 2
__global__ __launch_bounds__(1024) void k_s2s(
    const float* __restrict__ Wih, const float* __restrict__ Whh,
    const float* __restrict__ bih, const float* __restrict__ bhh,
    const bf16* __restrict__ h, const int* __restrict__ gstart,
    float* __restrict__ qstar, float* __restrict__ hh, float* __restrict__ cc, int first)
{
    int g0 = blockIdx.x * LG2;
    int t = threadIdx.x;
    __shared__ float qs[LG2][2 * D];
    __shared__ float hs[LG2][D];
    __shared__ float part[2][LG2][512];
    __shared__ float hnew[LG2][D];
    __shared__ float e_lds[POOL_CAP];
    __shared__ float redM[16], redS[16];
    __shared__ float rpart[8][D];

    for (int i = t; i < LG2 * 2 * D; i += 1024) {
        int g = i / (2 * D), c = i % (2 * D);
        qs[g][c] = first ? 0.f : qstar[(size_t)(g0 + g) * 2 * D + c];
    }
    for (int i = t; i < LG2 * D; i += 1024) {
        int g = i / D, c = i % D;
        hs[g][c] = first ? 0.f : hh[(size_t)(g0 + g) * D + c];
    }
    __syncthreads();

    int c = t & 511, half = t >> 9;
    float a0 = half ? 0.f : (bih[c] + bhh[c]);
    float a1 = a0;
    int qb = half * 128;
#pragma unroll 4
    for (int i = 0; i < 128; i++) {
        int k = qb + i;
        float wv = Wih[(size_t)k * 512 + c];
        a0 += qs[0][k] * wv;
        a1 += qs[1][k] * wv;
    }
    int hb = half * 64;
#pragma unroll 4
    for (int i = 0; i < 64; i++) {
        int k = hb + i;
        float wv = Whh[(size_t)k * 512 + c];
        a0 += hs[0][k] * wv;
        a1 += hs[1][k] * wv;
    }
    part[half][0][c] = a0;
    part[half][1][c] = a1;
    __syncthreads();

    if (t < LG2 * D) {
        int g = t >> 7, tt = t & 127;
        float gi = part[0][g][tt] + part[1][g][tt];
        float gf = part[0][g][D + tt] + part[1][g][D + tt];
        float gg2 = part[0][g][2 * D + tt] + part[1][g][2 * D + tt];
        float go = part[0][g][3 * D + tt] + part[1][g][3 * D + tt];
        float c_old = first ? 0.f : cc[(size_t)(g0 + g) * D + tt];
        float cn = sigm(gf) * c_old + sigm(gi) * ftanh(gg2);
        float hn = sigm(go) * ftanh(cn);
        cc[(size_t)(g0 + g) * D + tt] = cn;
        hh[(size_t)(g0 + g) * D + tt] = hn;
        qstar[(size_t)(g0 + g) * 2 * D + tt] = hn;
        hnew[g][tt] = hn;
    }
    __syncthreads();

    int w = t >> 6, l = t & 63;
    int dim = t & 127, h8 = t >> 7;
    const ushort* hu = (const ushort*)h;

    for (int gg = 0; gg < LG2; gg++) {
        int g = g0 + gg;
        int s0 = gstart[g], s1 = gstart[g + 1];
        s0 = s0 < 0 ? 0 : (s0 > N_NODES ? N_NODES : s0);
        s1 = s1 < s0 ? s0 : (s1 > N_NODES ? N_NODES : s1);
        int cnt = s1 - s0;

        float hq0 = hnew[gg][l];
        float hq1 = hnew[gg][64 + l];
        float m_run = -INFINITY, s_run = 0.f, racc = 0.f;

        for (int c0 = 0; c0 < cnt; c0 += POOL_CAP) {
            int clen = cnt - c0; if (clen > POOL_CAP) clen = POOL_CAP;

            for (int i = w; i < clen; i += 16) {
                int n = s0 + c0 + i;
                float v = bs2f((short)hu[(size_t)n * D + l]) * hq0
                        + bs2f((short)hu[(size_t)n * D + 64 + l]) * hq1;
#pragma unroll
                for (int off = 32; off > 0; off >>= 1) v += __shfl_down(v, off);
                if (l == 0) e_lds[i] = v;
            }
            __syncthreads();

            float m2 = -INFINITY;
            for (int i = t; i < clen; i += 1024) m2 = fmaxf(m2, e_lds[i]);
#pragma unroll
            for (int off = 32; off > 0; off >>= 1) m2 = fmaxf(m2, __shfl_down(m2, off));
            if (l == 0) redM[w] = m2;
            __syncthreads();
            m2 = -INFINITY;
#pragma unroll
            for (int i = 0; i < 16; i++) m2 = fmaxf(m2, redM[i]);
            float m_new = fmaxf(m_run, m2);
            float scale = (m_run == -INFINITY) ? 0.f : __expf(m_run - m_new);
            s_run *= scale;
            racc *= scale;
            __syncthreads();

            float s = 0.f;
            for (int i = t; i < clen; i += 1024) {
                float wv = __expf(e_lds[i] - m_new);
                e_lds[i] = wv;
                s += wv;
            }
#pragma unroll
            for (int off = 32; off > 0; off >>= 1) s += __shfl_down(s, off);
            if (l == 0) redS[w] = s;
            __syncthreads();
#pragma unroll
            for (int i = 0; i < 16; i++) s_run += redS[i];

            for (int i = h8; i < clen; i += 8)
                racc += e_lds[i] * bs2f((short)hu[(size_t)(s0 + c0 + i) * D + dim]);
            m_run = m_new;
            __syncthreads();
        }

        rpart[h8][dim] = racc;
        __syncthreads();
        if (t < D) {
            float inv = 1.f / (s_run + 1e-16f);
            float r = 0.f;
#pragma unroll
            for (int i = 0; i < 8; i++) r += rpart[i][t];
            qstar[(size_t)g * 2 * D + D + t] = r * inv;
        }
        __syncthreads();
    }
}

// ---------------------------------------------------------------------------
// Head: y = leaky(q_star@W_lin + b_lin) @ W_fin + b_fin   -> fp32 out
// ---------------------------------------------------------------------------
__global__ __launch_bounds__(128) void k_final(
    const float* __restrict__ qstar, const float* __restrict__ Wlin, const float* __restrict__ blin,
    const float* __restrict__ Wfin, const float* __restrict__ bfin, float* __restrict__ outp)
{
    int g = blockIdx.x, t = threadIdx.x;
    __shared__ float qs[2 * D], ts[D];
    qs[t] = qstar[(size_t)g * 2 * D + t];
    qs[D + t] = qstar[(size_t)g * 2 * D + D + t];
    __syncthreads();

    float acc = blin[t];
    for (int k = 0; k < 2 * D; k++) acc += qs[k] * Wlin[(size_t)k * D + t];
    ts[t] = leaky(acc);
    __syncthreads();

    if (t < L_DIM) {
        float a2 = bfin[t];
        for (int k = 0; k < D; k++) a2 += ts[k] * Wfin[(size_t)k * L_DIM + t];
        outp[(size_t)g * L_DIM + t] = a2;
    }
}

// ---------------------------------------------------------------------------
extern "C" void kernel_launch(void* const* d_in, const int* in_sizes, int n_in,
                              void* d_out, int out_size, void* d_ws, size_t ws_size,
                              hipStream_t stream)
{
    const float* x      = (const float*)d_in[0];
    const int*   ei     = (const int*)d_in[1];
    const int*   batch  = (const int*)d_in[3];
    const float* Wemb   = (const float*)d_in[4];
    const float* bemb   = (const float*)d_in[5];
    const float* Wfirst = (const float*)d_in[6];
    const float* bfirst = (const float*)d_in[7];
    const float* Wl     = (const float*)d_in[8];
    const float* bl     = (const float*)d_in[9];
    const float* Wr     = (const float*)d_in[10];
    const float* gWih   = (const float*)d_in[11];
    const float* gWhh   = (const float*)d_in[12];
    const float* gbih   = (const float*)d_in[13];
    const float* gbhh   = (const float*)d_in[14];
    const float* lWih   = (const float*)d_in[15];
    const float* lWhh   = (const float*)d_in[16];
    const float* lbih   = (const float*)d_in[17];
    const float* lbhh   = (const float*)d_in[18];
    const float* Wlin   = (const float*)d_in[19];
    const float* blin   = (const float*)d_in[20];
    const float* Wfin   = (const float*)d_in[21];
    const float* bfin   = (const float*)d_in[22];
    float* outp = (float*)d_out;

    // ---- workspace carve (256B-aligned slabs), ~46 MB ----
    size_t o = 0;
    char* base = (char*)d_ws;
    auto carve = [&](size_t bytes) { void* p = base + o; o += (bytes + 255) & ~(size_t)255; return p; };
    bf16*  h0     = (bf16*)carve((size_t)N_NODES * D * sizeof(bf16));
    bf16*  h1     = (bf16*)carve((size_t)N_NODES * D * sizeof(bf16));
    bf16*  mbuf   = (bf16*)carve((size_t)N_NODES * D * sizeof(bf16));
    int*   offs   = (int*)carve((size_t)SCAN_N * sizeof(int));
    int*   srcs   = (int*)carve((size_t)N_EDGES * sizeof(int));
    int*   bcnt   = (int*)carve((size_t)(NBUCK + 1) * sizeof(int));
    int*   bcur   = (int*)carve((size_t)NBUCK * sizeof(int));
    uint*  ebuf   = (uint*)carve((size_t)N_EDGES * sizeof(uint));
    float* hh     = (float*)carve((size_t)N_GRAPHS * D * sizeof(float));
    float* cc     = (float*)carve((size_t)N_GRAPHS * D * sizeof(float));
    float* qstar  = (float*)carve((size_t)N_GRAPHS * 2 * D * sizeof(float));
    int*   gstart = (int*)carve((size_t)(N_GRAPHS + 1) * sizeof(int));
    short* W1p    = (short*)carve((size_t)256 * 128 * sizeof(short));
    short* W2p    = (short*)carve((size_t)256 * 384 * sizeof(short));
    size_t need = o;

    if (ws_size < need) {
        k_signal<<<(out_size + 255) / 256, 256, 0, stream>>>(outp, out_size);
        return;
    }

    // node MLP -> h0
    k_embed<<<N_NODES / NPE, 128, 0, stream>>>(x, Wemb, bemb, Wfirst, bfirst, h0);

    // all weight packing (32768 W1 + 98304 W2 threads)
    k_pack_all<<<(32768 + 98304) / 256, 256, 0, stream>>>(Wl, Wr, gWih, gWhh, W1p, W2p);

    // bucketed CSR build (LDS-aggregated placement)
    hipMemsetAsync(bcnt, 0, (size_t)((char*)ebuf - (char*)bcnt), stream);
    k_bcount<<<128, 256, 0, stream>>>(ei, bcnt);
    k_bscan<<<1, 64, 0, stream>>>(bcnt);
    k_bfill2<<<(N_EDGES + EPB - 1) / EPB, BFT, 0, stream>>>(ei, bcnt, bcur, ebuf);
    k_csr<<<NBUCK, 256, 0, stream>>>(bcnt, ebuf, offs, srcs);

    // graph segment starts
    k_gstart<<<(N_GRAPHS + 1 + 255) / 256, 256, 0, stream>>>(batch, gstart);

    // 3 message-passing steps: gather -> SAGE linear (persistent) -> GRU (persistent)
    bf16* hc = h0; bf16* hn = h1;
    for (int s = 0; s < 3; s++) {
        k_gather<<<N_NODES / 4, 256, 0, stream>>>(hc, hn, offs, srcs);
        k_sage1<<<256, 512, 0, stream>>>(hn, hc, W1p, bl, mbuf);
        k_gru2<<<256, 512, 0, stream>>>(mbuf, hc, W2p, gbih, gbhh, hn);
        bf16* tmp = hc; hc = hn; hn = tmp;
    }

    // Set2Set: merged LSTM+pool, 2 graphs/block
    for (int s = 0; s < 3; s++) {
        k_s2s<<<N_GRAPHS / LG2, 1024, 0, stream>>>(lWih, lWhh, lbih, lbhh,
                                                   hc, gstart, qstar, hh, cc, s == 0);
    }

    k_final<<<N_GRAPHS, 128, 0, stream>>>(qstar, Wlin, blin, Wfin, bfin, outp);
}

// Round 10
// 465.074 us; speedup vs baseline: 1.5550x; 1.2070x over previous
//
#include <hip/hip_runtime.h>
#include <hip/hip_bf16.h>
#include <math.h>

#define N_NODES 50000
#define N_EDGES 800000
#define N_GRAPHS 512
#define F_IN 16
#define E_DIM 64
#define D 128
#define L_DIM 64
#define NEG_SLOPE 0.01f

#define SCAN_N (N_NODES + 1)                  // 50001
#define NBUCK ((N_NODES + 127) >> 7)          // 391 buckets of 128 nodes
#define EPT 4
#define BFT 1024
#define EPB (BFT * EPT)                       // 4096 edges per block

typedef __hip_bfloat16 bf16;
typedef unsigned int uint;
typedef unsigned short ushort;
typedef __attribute__((ext_vector_type(8))) short short8;
typedef __attribute__((ext_vector_type(4))) float float4v;

__device__ __forceinline__ float b2f(bf16 v) { return __bfloat162float(v); }
__device__ __forceinline__ bf16  f2b(float v) { return __float2bfloat16(v); }
__device__ __forceinline__ short f2bs(float f) { bf16 b = __float2bfloat16(f); return *reinterpret_cast<short*>(&b); }
__device__ __forceinline__ float bs2f(short s) { return __uint_as_float(((uint)(ushort)s) << 16); }
__device__ __forceinline__ float leaky(float v) { return v > 0.f ? v : NEG_SLOPE * v; }

// fast transcendentals: v_exp_f32 / v_rcp_f32 based (libm expf/tanhf are
// 13/30-instr branchy sequences). Outputs round to bf16 downstream.
__device__ __forceinline__ float frcp(float x) { return __builtin_amdgcn_rcpf(x); }
__device__ __forceinline__ float sigm(float v) { return frcp(1.f + __expf(-v)); }
__device__ __forceinline__ float ftanh(float v)
{
    v = fminf(15.f, fmaxf(-15.f, v));   // clamp so __expf never overflows
    float a = __expf(2.f * v);
    return (a - 1.f) * frcp(a + 1.f);
}

// ---------------------------------------------------------------------------
__global__ __launch_bounds__(256) void k_signal(float* outp, int n)
{
    int i = blockIdx.x * 256 + threadIdx.x;
    if (i < n) outp[i] = 1.0f;
}

// ---------------------------------------------------------------------------
// h0 = leaky(leaky(x@W_emb + b_emb) @ W_first + b_first)  -> bf16
// ---------------------------------------------------------------------------
#define NPE 16
__global__ __launch_bounds__(128) void k_embed(
    const float* __restrict__ x, const float* __restrict__ Wemb, const float* __restrict__ bemb,
    const float* __restrict__ Wfirst, const float* __restrict__ bfirst, bf16* __restrict__ out)
{
    __shared__ float xs[NPE][F_IN];
    __shared__ float ys[NPE][E_DIM];
    int t = threadIdx.x;
    int base = blockIdx.x * NPE;

    for (int i = t; i < NPE * F_IN; i += 128)
        xs[i / F_IN][i % F_IN] = x[(size_t)base * F_IN + i];
    __syncthreads();

    if (t < E_DIM) {
        float acc[NPE];
#pragma unroll
        for (int nn = 0; nn < NPE; nn++) acc[nn] = 0.f;
        for (int k = 0; k < F_IN; k++) {
            float w = Wemb[k * E_DIM + t];
#pragma unroll
            for (int nn = 0; nn < NPE; nn++) acc[nn] += xs[nn][k] * w;
        }
        float bb = bemb[t];
#pragma unroll
        for (int nn = 0; nn < NPE; nn++) ys[nn][t] = leaky(acc[nn] + bb);
    }
    __syncthreads();

    {
        float acc[NPE];
#pragma unroll
        for (int nn = 0; nn < NPE; nn++) acc[nn] = 0.f;
        for (int k = 0; k < E_DIM; k++) {
            float w = Wfirst[k * D + t];
#pragma unroll
            for (int nn = 0; nn < NPE; nn++) acc[nn] += ys[nn][k] * w;
        }
        float bb = bfirst[t];
#pragma unroll
        for (int nn = 0; nn < NPE; nn++)
            out[(size_t)(base + nn) * D + t] = f2b(leaky(acc[nn] + bb));
    }
}

// ---------------------------------------------------------------------------
// Bucketed CSR build.
// ---------------------------------------------------------------------------
__global__ __launch_bounds__(256) void k_bcount(const int* __restrict__ ei, int* __restrict__ bcnt)
{
    __shared__ int lc[NBUCK];
    for (int i = threadIdx.x; i < NBUCK; i += 256) lc[i] = 0;
    __syncthreads();
    int stride = gridDim.x * 256;
    for (int e = blockIdx.x * 256 + threadIdx.x; e < N_EDGES; e += stride) {
        int d = ei[N_EDGES + e];
        d = d < 0 ? 0 : (d >= N_NODES ? N_NODES - 1 : d);
        atomicAdd(&lc[d >> 7], 1);
    }
    __syncthreads();
    for (int i = threadIdx.x; i < NBUCK; i += 256)
        if (lc[i]) atomicAdd(&bcnt[i + 1], lc[i]);
}

__global__ void k_bscan(int* __restrict__ bcnt)
{
    if (threadIdx.x == 0 && blockIdx.x == 0) {
        int run = 0;
        for (int i = 0; i <= NBUCK; i++) { run += bcnt[i]; bcnt[i] = run; }
    }
}

__global__ __launch_bounds__(BFT) void k_bfill2(
    const int* __restrict__ ei, const int* __restrict__ bstart,
    int* __restrict__ bcur, uint* __restrict__ ebuf)
{
    __shared__ int lcnt[NBUCK];
    __shared__ int lbase[NBUCK];
    int t = threadIdx.x;
    int e0 = blockIdx.x * EPB;

    for (int i = t; i < NBUCK; i += BFT) lcnt[i] = 0;
    __syncthreads();

    uint pk[EPT];
    int bb[EPT];
#pragma unroll
    for (int q = 0; q < EPT; q++) {
        int e = e0 + q * BFT + t;          // coalesced reads
        bb[q] = -1;
        if (e < N_EDGES) {
            int s = ei[e];
            int d = ei[N_EDGES + e];
            s = s < 0 ? 0 : (s >= N_NODES ? N_NODES - 1 : s);
            d = d < 0 ? 0 : (d >= N_NODES ? N_NODES - 1 : d);
            bb[q] = d >> 7;
            pk[q] = ((uint)(d & 127) << 16) | (uint)s;
            atomicAdd(&lcnt[bb[q]], 1);    // LDS atomic (fast)
        }
    }
    __syncthreads();

    for (int i = t; i < NBUCK; i += BFT) {
        int cv = lcnt[i];
        lbase[i] = cv > 0 ? atomicAdd(&bcur[i], cv) : 0;
    }
    __syncthreads();
    for (int i = t; i < NBUCK; i += BFT) lcnt[i] = 0;   // reuse as cursor
    __syncthreads();

#pragma unroll
    for (int q = 0; q < EPT; q++) {
        if (bb[q] >= 0) {
            int pos = lbase[bb[q]] + atomicAdd(&lcnt[bb[q]], 1);
            int slot = bstart[bb[q]] + pos;
            if (slot >= 0 && slot < N_EDGES) ebuf[slot] = pk[q];
        }
    }
}

__global__ __launch_bounds__(256) void k_csr(
    const int* __restrict__ bstart, const uint* __restrict__ ebuf,
    int* __restrict__ offs, int* __restrict__ srcs)
{
    __shared__ int cnt[128];
    __shared__ int loffs[129];
    int b = blockIdx.x, t = threadIdx.x;
    int e0 = bstart[b], e1 = bstart[b + 1];
    if (t < 128) cnt[t] = 0;
    __syncthreads();
    for (int j = e0 + t; j < e1; j += 256)
        atomicAdd(&cnt[(ebuf[j] >> 16) & 127], 1);
    __syncthreads();
    if (t == 0) {
        int run = 0;
        for (int i = 0; i < 128; i++) { loffs[i] = run; run += cnt[i]; }
        loffs[128] = run;
    }
    __syncthreads();
    int n0 = b << 7;
    if (t < 128) {
        int n = n0 + t;
        if (n <= N_NODES) offs[n] = e0 + loffs[t];
        cnt[t] = 0;
    }
    __syncthreads();
    for (int j = e0 + t; j < e1; j += 256) {
        uint pk = ebuf[j];
        int dl = (pk >> 16) & 127;
        int rank = atomicAdd(&cnt[dl], 1);
        int slot = e0 + loffs[dl] + rank;
        if (slot >= 0 && slot < N_EDGES) srcs[slot] = (int)(pk & 0xffffu);
    }
}

// ---------------------------------------------------------------------------
__global__ __launch_bounds__(256) void k_gstart(const int* __restrict__ batch, int* __restrict__ gstart)
{
    int g = blockIdx.x * 256 + threadIdx.x;
    if (g > N_GRAPHS) return;
    int lo = 0, hi = N_NODES;
    while (lo < hi) {
        int mid = (lo + hi) >> 1;
        if (batch[mid] < g) lo = mid + 1; else hi = mid;
    }
    gstart[g] = lo;
}

// ---------------------------------------------------------------------------
// Weight packing, PHASE-ORDERED (R3 layout):
//   W1p : frag f = ct*8 + k0
//   Wihp/Whhp: frag f = ph*4 + k0, ph = ct*3 + p  (p = GRU gate)
// ---------------------------------------------------------------------------
__global__ __launch_bounds__(256) void k_pack_all(
    const float* __restrict__ Wl, const float* __restrict__ Wr,
    const float* __restrict__ gWih, const float* __restrict__ gWhh,
    short* __restrict__ W1p, short* __restrict__ Wihp, short* __restrict__ Whhp)
{
    int tid = blockIdx.x * 256 + threadIdx.x;     // 131072 total
    if (tid < 32768) {
        int j = tid & 7, l = (tid >> 3) & 63, frag = tid >> 9;
        int nb = frag >> 3, kb = frag & 7;        // phase-major: frag = ct*8 + k0
        int k = kb * 32 + ((l >> 4) * 8) + j;
        int n = nb * 16 + (l & 15);
        float v = (k < 128) ? Wl[k * D + n] : Wr[(k - 128) * D + n];
        W1p[tid] = f2bs(v);
    } else {
        int id = tid - 32768;
        const float* W = gWih;
        short* Wp = Wihp;
        if (id >= 49152) { id -= 49152; W = gWhh; Wp = Whhp; }
        int j = id & 7, l = (id >> 3) & 63, f = id >> 9;   // f in [0,96)
        int ph = f >> 2, k0 = f & 3;              // frag = ph*4 + k0
        int ct = ph / 3, p = ph - ct * 3;
        int k = k0 * 32 + ((l >> 4) * 8) + j;
        int n = p * 128 + ct * 16 + (l & 15);     // gates are 128-col blocks
        Wp[id] = f2bs(W[k * 384 + n]);
    }
}

// ---------------------------------------------------------------------------
// Batched neighbor gather: wave covers 4 rows per dwordx4 (16 lanes x 16B),
// 16 rows in flight in the bulk loop, masked 16-row epilogue (all loads
// issued before use).  Replaces the old serial 1-edge tail that cost up to
// ~7 dependent L3 round trips (~450 cyc each) per node at mean degree 16.
// grp = l>>4 selects the row within a 4-row batch; q = l&15 the 16B slice.
// ---------------------------------------------------------------------------
__global__ __launch_bounds__(256) void k_gather(
    const bf16* __restrict__ hin, bf16* __restrict__ hagg,
    const int* __restrict__ offs, const int* __restrict__ srcs)
{
    int w = threadIdx.x >> 6, l = threadIdx.x & 63;
    int grp = l >> 4, q = l & 15;
    int n = blockIdx.x * 4 + w;
    const ushort* hinu = (const ushort*)hin;
    int j0 = offs[n], j1 = offs[n + 1];
    j0 = j0 < 0 ? 0 : (j0 > N_EDGES ? N_EDGES : j0);
    j1 = j1 < j0 ? j0 : (j1 > N_EDGES ? N_EDGES : j1);

    float acc[8];
#pragma unroll
    for (int i = 0; i < 8; i++) acc[i] = 0.f;

    int j = j0;
    // bulk: 16 rows / iteration, 4 dwordx4 loads in flight per lane
    for (; j + 15 < j1; j += 16) {
        int s0 = srcs[j + grp];
        int s1 = srcs[j + 4 + grp];
        int s2 = srcs[j + 8 + grp];
        int s3 = srcs[j + 12 + grp];
        s0 = s0 < 0 ? 0 : (s0 >= N_NODES ? N_NODES - 1 : s0);
        s1 = s1 < 0 ? 0 : (s1 >= N_NODES ? N_NODES - 1 : s1);
        s2 = s2 < 0 ? 0 : (s2 >= N_NODES ? N_NODES - 1 : s2);
        s3 = s3 < 0 ? 0 : (s3 >= N_NODES ? N_NODES - 1 : s3);
        short8 v0 = *(const short8*)(hinu + (size_t)s0 * D + q * 8);
        short8 v1 = *(const short8*)(hinu + (size_t)s1 * D + q * 8);
        short8 v2 = *(const short8*)(hinu + (size_t)s2 * D + q * 8);
        short8 v3 = *(const short8*)(hinu + (size_t)s3 * D + q * 8);
#pragma unroll
        for (int i = 0; i < 8; i++)
            acc[i] += (bs2f(v0[i]) + bs2f(v1[i])) + (bs2f(v2[i]) + bs2f(v3[i]));
    }
    // masked epilogue: 1..15 remaining rows, all loads issued before use
    if (j < j1) {
        int i0 = j + grp, i1 = j + 4 + grp, i2 = j + 8 + grp, i3 = j + 12 + grp;
        bool b0 = i0 < j1, b1 = i1 < j1, b2 = i2 < j1, b3 = i3 < j1;
        int c0 = b0 ? i0 : j1 - 1;
        int c1 = b1 ? i1 : j1 - 1;
        int c2 = b2 ? i2 : j1 - 1;
        int c3 = b3 ? i3 : j1 - 1;
        int s0 = srcs[c0], s1 = srcs[c1], s2 = srcs[c2], s3 = srcs[c3];
        s0 = s0 < 0 ? 0 : (s0 >= N_NODES ? N_NODES - 1 : s0);
        s1 = s1 < 0 ? 0 : (s1 >= N_NODES ? N_NODES - 1 : s1);
        s2 = s2 < 0 ? 0 : (s2 >= N_NODES ? N_NODES - 1 : s2);
        s3 = s3 < 0 ? 0 : (s3 >= N_NODES ? N_NODES - 1 : s3);
        short8 v0 = *(const short8*)(hinu + (size_t)s0 * D + q * 8);
        short8 v1 = *(const short8*)(hinu + (size_t)s1 * D + q * 8);
        short8 v2 = *(const short8*)(hinu + (size_t)s2 * D + q * 8);
        short8 v3 = *(const short8*)(hinu + (size_t)s3 * D + q * 8);
        if (b0) {
#pragma unroll
            for (int i = 0; i < 8; i++) acc[i] += bs2f(v0[i]);
        }
        if (b1) {
#pragma unroll
            for (int i = 0; i < 8; i++) acc[i] += bs2f(v1[i]);
        }
        if (b2) {
#pragma unroll
            for (int i = 0; i < 8; i++) acc[i] += bs2f(v2[i]);
        }
        if (b3) {
#pragma unroll
            for (int i = 0; i < 8; i++) acc[i] += bs2f(v3[i]);
        }
    }

    // combine the 4 row-groups: lanes {q, q+16, q+32, q+48} hold same dims
#pragma unroll
    for (int i = 0; i < 8; i++) {
        acc[i] += __shfl_xor(acc[i], 16);
        acc[i] += __shfl_xor(acc[i], 32);
    }
    if (grp == 0) {
        short8 outv;
#pragma unroll
        for (int i = 0; i < 8; i++) outv[i] = f2bs(acc[i]);
        *(short8*)((ushort*)hagg + (size_t)n * D + q * 8) = outv;
    }
}

// ---------------------------------------------------------------------------
// Fused SAGE + GRU via MFMA (R3 structure — best measured: 43.4 us/step).
// 64 rows/block, 256 threads = 4 waves.  Wave (rg,cg): rg = row group
// (32 rows), cg = column half (4 of 8 ct tiles).  B register double-buffer.
// ---------------------------------------------------------------------------
#define M_STR 136
__global__ __launch_bounds__(256) void k_sage_gru_mfma(
    const bf16* __restrict__ hin, bf16* __restrict__ hagg_out,
    const short* __restrict__ W1p, const short* __restrict__ Wihp, const short* __restrict__ Whhp,
    const float* __restrict__ bl, const float* __restrict__ bih, const float* __restrict__ bhh)
{
    __shared__ short Msh[64 * M_STR];   // 17408 B
    __shared__ short Hsh[64 * M_STR];   // 17408 B
    int t = threadIdx.x;
    int w = t >> 6, l = t & 63;
    int rg = w >> 1, cg = w & 1;
    int base = blockIdx.x * 64;
    const ushort* hinu = (const ushort*)hin;
    const ushort* haggu = (const ushort*)hagg_out;
    ushort* houtu = (ushort*)hagg_out;

    int rA = base + rg * 32 + (l & 15);
    int rB = rA + 16;
    int rcA = rA < N_NODES ? rA : N_NODES - 1;
    int rcB = rB < N_NODES ? rB : N_NODES - 1;
    int koff = (l >> 4) * 8;

    short8 afrA[8], afrB[8];
#pragma unroll
    for (int k0 = 0; k0 < 4; k0++) {
        afrA[k0]     = *(const short8*)(haggu + (size_t)rcA * D + k0 * 32 + koff);
        afrB[k0]     = *(const short8*)(haggu + (size_t)rcB * D + k0 * 32 + koff);
        afrA[4 + k0] = *(const short8*)(hinu + (size_t)rcA * D + k0 * 32 + koff);
        afrB[4 + k0] = *(const short8*)(hinu + (size_t)rcB * D + k0 * 32 + koff);
    }

    int mrowA = rg * 32 + (l & 15);
    int mrowB = mrowA + 16;
    int crowA = rg * 32 + (l >> 4) * 4;
    int crowB = crowA + 16;

    // park h tile in LDS (one column-group wave per row group writes it)
    if (cg == 0) {
#pragma unroll
        for (int k0 = 0; k0 < 4; k0++) {
            *(short8*)&Hsh[mrowA * M_STR + k0 * 32 + koff] = afrA[4 + k0];
            *(short8*)&Hsh[mrowB * M_STR + k0 * 32 + koff] = afrB[4 + k0];
        }
    }

    // ---- GEMM1: m = relu([agg|h] @ W1 + b_l) -> Msh, 4 ct tiles per wave ----
    const short* w1 = W1p + cg * 16384;            // cg*4 ct-tiles * 4096 shorts
    short8 bA[8], bB[8];
#pragma unroll
    for (int k0 = 0; k0 < 8; k0++)
        bA[k0] = *(const short8*)&w1[k0 * 512 + l * 8];
#pragma unroll
    for (int cti = 0; cti < 4; cti++) {
        int ct = cg * 4 + cti;
        const short8* bc = (cti & 1) ? bB : bA;
        short8* bn = (cti & 1) ? bA : bB;
        if (cti < 3) {
#pragma unroll
            for (int k0 = 0; k0 < 8; k0++)
                bn[k0] = *(const short8*)&w1[(cti + 1) * 4096 + k0 * 512 + l * 8];
        }
        float4v accA = {0.f, 0.f, 0.f, 0.f};
        float4v accB = {0.f, 0.f, 0.f, 0.f};
#pragma unroll
        for (int k0 = 0; k0 < 8; k0++) {
            accA = __builtin_amdgcn_mfma_f32_16x16x32_bf16(afrA[k0], bc[k0], accA, 0, 0, 0);
            accB = __builtin_amdgcn_mfma_f32_16x16x32_bf16(afrB[k0], bc[k0], accB, 0, 0, 0);
        }
        float bb = bl[ct * 16 + (l & 15)];
#pragma unroll
        for (int i = 0; i < 4; i++) {
            float vA = accA[i] + bb;
            float vB = accB[i] + bb;
            Msh[(crowA + i) * M_STR + ct * 16 + (l & 15)] = f2bs(vA > 0.f ? vA : 0.f);
            Msh[(crowB + i) * M_STR + ct * 16 + (l & 15)] = f2bs(vB > 0.f ? vB : 0.f);
        }
    }
    __syncthreads();

    short8 amrA[4], amrB[4];
#pragma unroll
    for (int k0 = 0; k0 < 4; k0++) {
        amrA[k0] = *(const short8*)&Msh[mrowA * M_STR + k0 * 32 + koff];
        amrB[k0] = *(const short8*)&Msh[mrowB * M_STR + k0 * 32 + koff];
    }

    // ---- GEMM2 + GRU epilogue: 12 phases/wave (4 ct x 3 gates) ----
    const short* wip = Wihp + cg * 24576;          // cg*12 phases * 2048 shorts
    const short* whp = Whhp + cg * 24576;
    short8 iA[4], hA[4], iB[4], hB[4];
#pragma unroll
    for (int k0 = 0; k0 < 4; k0++) {
        iA[k0] = *(const short8*)&wip[k0 * 512 + l * 8];
        hA[k0] = *(const short8*)&whp[k0 * 512 + l * 8];
    }
#pragma unroll
    for (int cti = 0; cti < 4; cti++) {
        int ct = cg * 4 + cti;
        int c = ct * 16 + (l & 15);
        float rvA[4], zvA[4], rvB[4], zvB[4];
#pragma unroll
        for (int p = 0; p < 3; p++) {
            int phl = cti * 3 + p;
            const short8* wi = (phl & 1) ? iB : iA;
            const short8* wh = (phl & 1) ? hB : hA;
            short8* win = (phl & 1) ? iA : iB;
            short8* whn = (phl & 1) ? hA : hB;
            if (phl < 11) {
#pragma unroll
                for (int k0 = 0; k0 < 4; k0++) {
                    win[k0] = *(const short8*)&wip[(phl + 1) * 2048 + k0 * 512 + l * 8];
                    whn[k0] = *(const short8*)&whp[(phl + 1) * 2048 + k0 * 512 + l * 8];
                }
            }
            float4v aiA = {0.f, 0.f, 0.f, 0.f};
            float4v ahA = {0.f, 0.f, 0.f, 0.f};
            float4v aiB = {0.f, 0.f, 0.f, 0.f};
            float4v ahB = {0.f, 0.f, 0.f, 0.f};
#pragma unroll
            for (int k0 = 0; k0 < 4; k0++) {
                aiA = __builtin_amdgcn_mfma_f32_16x16x32_bf16(amrA[k0], wi[k0], aiA, 0, 0, 0);
                ahA = __builtin_amdgcn_mfma_f32_16x16x32_bf16(afrA[4 + k0], wh[k0], ahA, 0, 0, 0);
                aiB = __builtin_amdgcn_mfma_f32_16x16x32_bf16(amrB[k0], wi[k0], aiB, 0, 0, 0);
                ahB = __builtin_amdgcn_mfma_f32_16x16x32_bf16(afrB[4 + k0], wh[k0], ahB, 0, 0, 0);
            }
            float bis = bih[p * 128 + c];
            float bhs = bhh[p * 128 + c];
            if (p == 0) {
#pragma unroll
                for (int i = 0; i < 4; i++) {
                    rvA[i] = sigm(aiA[i] + bis + ahA[i] + bhs);
                    rvB[i] = sigm(aiB[i] + bis + ahB[i] + bhs);
                }
            } else if (p == 1) {
#pragma unroll
                for (int i = 0; i < 4; i++) {
                    zvA[i] = sigm(aiA[i] + bis + ahA[i] + bhs);
                    zvB[i] = sigm(aiB[i] + bis + ahB[i] + bhs);
                }
            } else {
#pragma unroll
                for (int i = 0; i < 4; i++) {
                    int gA = base + crowA + i;
                    float h0A = bs2f(Hsh[(crowA + i) * M_STR + c]);
                    float nA = ftanh(aiA[i] + bis + rvA[i] * (ahA[i] + bhs));
                    if (gA < N_NODES)
                        houtu[(size_t)gA * D + c] = (ushort)f2bs((1.f - zvA[i]) * nA + zvA[i] * h0A);
                    int gB = base + crowB + i;
                    float h0B = bs2f(Hsh[(crowB + i) * M_STR + c]);
                    float nB = ftanh(aiB[i] + bis + rvB[i] * (ahB[i] + bhs));
                    if (gB < N_NODES)
                        houtu[(size_t)gB * D + c] = (ushort)f2bs((1.f - zvB[i]) * nB + zvB[i] * h0B);
                }
            }
        }
    }
}

// ---------------------------------------------------------------------------
// Merged Set2Set step: LSTM + pool, 2 graphs per block.
// ---------------------------------------------------------------------------
#define POOL_CAP 1024
#define LG2 2
__global__ __launch_bounds__(1024) void k_s2s(
    const float* __restrict__ Wih, const float* __restrict__ Whh,
    const float* __restrict__ bih, const float* __restrict__ bhh,
    const bf16* __restrict__ h, const int* __restrict__ gstart,
    float* __restrict__ qstar, float* __restrict__ hh, float* __restrict__ cc, int first)
{
    int g0 = blockIdx.x * LG2;
    int t = threadIdx.x;
    __shared__ float qs[LG2][2 * D];
    __shared__ float hs[LG2][D];
    __shared__ float part[2][LG2][512];
    __shared__ float hnew[LG2][D];
    __shared__ float e_lds[POOL_CAP];
    __shared__ float redM[16], redS[16];
    __shared__ float rpart[8][D];

    for (int i = t; i < LG2 * 2 * D; i += 1024) {
        int g = i / (2 * D), c = i % (2 * D);
        qs[g][c] = first ? 0.f : qstar[(size_t)(g0 + g) * 2 * D + c];
    }
    for (int i = t; i < LG2 * D; i += 1024) {
        int g = i / D, c = i % D;
        hs[g][c] = first ? 0.f : hh[(size_t)(g0 + g) * D + c];
    }
    __syncthreads();

    int c = t & 511, half = t >> 9;
    float a0 = half ? 0.f : (bih[c] + bhh[c]);
    float a1 = a0;
    int qb = half * 128;
#pragma unroll 4
    for (int i = 0; i < 128; i++) {
        int k = qb + i;
        float wv = Wih[(size_t)k * 512 + c];
        a0 += qs[0][k] * wv;
        a1 += qs[1][k] * wv;
    }
    int hb = half * 64;
#pragma unroll 4
    for (int i = 0; i < 64; i++) {
        int k = hb + i;
        float wv = Whh[(size_t)k * 512 + c];
        a0 += hs[0][k] * wv;
        a1 += hs[1][k] * wv;
    }
    part[half][0][c] = a0;
    part[half][1][c] = a1;
    __syncthreads();

    if (t < LG2 * D) {
        int g = t >> 7, tt = t & 127;
        float gi = part[0][g][tt] + part[1][g][tt];
        float gf = part[0][g][D + tt] + part[1][g][D + tt];
        float gg2 = part[0][g][2 * D + tt] + part[1][g][2 * D + tt];
        float go = part[0][g][3 * D + tt] + part[1][g][3 * D + tt];
        float c_old = first ? 0.f : cc[(size_t)(g0 + g) * D + tt];
        float cn = sigm(gf) * c_old + sigm(gi) * ftanh(gg2);
        float hn = sigm(go) * ftanh(cn);
        cc[(size_t)(g0 + g) * D + tt] = cn;
        hh[(size_t)(g0 + g) * D + tt] = hn;
        qstar[(size_t)(g0 + g) * 2 * D + tt] = hn;
        hnew[g][tt] = hn;
    }
    __syncthreads();

    int w = t >> 6, l = t & 63;
    int dim = t & 127, h8 = t >> 7;
    const ushort* hu = (const ushort*)h;

    for (int gg = 0; gg < LG2; gg++) {
        int g = g0 + gg;
        int s0 = gstart[g], s1 = gstart[g + 1];
        s0 = s0 < 0 ? 0 : (s0 > N_NODES ? N_NODES : s0);
        s1 = s1 < s0 ? s0 : (s1 > N_NODES ? N_NODES : s1);
        int cnt = s1 - s0;

        float hq0 = hnew[gg][l];
        float hq1 = hnew[gg][64 + l];
        float m_run = -INFINITY, s_run = 0.f, racc = 0.f;

        for (int c0 = 0; c0 < cnt; c0 += POOL_CAP) {
            int clen = cnt - c0; if (clen > POOL_CAP) clen = POOL_CAP;

            for (int i = w; i < clen; i += 16) {
                int n = s0 + c0 + i;
                float v = bs2f((short)hu[(size_t)n * D + l]) * hq0
                        + bs2f((short)hu[(size_t)n * D + 64 + l]) * hq1;
#pragma unroll
                for (int off = 32; off > 0; off >>= 1) v += __shfl_down(v, off);
                if (l == 0) e_lds[i] = v;
            }
            __syncthreads();

            float m2 = -INFINITY;
            for (int i = t; i < clen; i += 1024) m2 = fmaxf(m2, e_lds[i]);
#pragma unroll
            for (int off = 32; off > 0; off >>= 1) m2 = fmaxf(m2, __shfl_down(m2, off));
            if (l == 0) redM[w] = m2;
            __syncthreads();
            m2 = -INFINITY;
#pragma unroll
            for (int i = 0; i < 16; i++) m2 = fmaxf(m2, redM[i]);
            float m_new = fmaxf(m_run, m2);
            float scale = (m_run == -INFINITY) ? 0.f : __expf(m_run - m_new);
            s_run *= scale;
            racc *= scale;
            __syncthreads();

            float s = 0.f;
            for (int i = t; i < clen; i += 1024) {
                float wv = __expf(e_lds[i] - m_new);
                e_lds[i] = wv;
                s += wv;
            }
#pragma unroll
            for (int off = 32; off > 0; off >>= 1) s += __shfl_down(s, off);
            if (l == 0) redS[w] = s;
            __syncthreads();
#pragma unroll
            for (int i = 0; i < 16; i++) s_run += redS[i];

            for (int i = h8; i < clen; i += 8)
                racc += e_lds[i] * bs2f((short)hu[(size_t)(s0 + c0 + i) * D + dim]);
            m_run = m_new;
            __syncthreads();
        }

        rpart[h8][dim] = racc;
        __syncthreads();
        if (t < D) {
            float inv = 1.f / (s_run + 1e-16f);
            float r = 0.f;
#pragma unroll
            for (int i = 0; i < 8; i++) r += rpart[i][t];
            qstar[(size_t)g * 2 * D + D + t] = r * inv;
        }
        __syncthreads();
    }
}

// ---------------------------------------------------------------------------
// Head: y = leaky(q_star@W_lin + b_lin) @ W_fin + b_fin   -> fp32 out
// ---------------------------------------------------------------------------
__global__ __launch_bounds__(128) void k_final(
    const float* __restrict__ qstar, const float* __restrict__ Wlin, const float* __restrict__ blin,
    const float* __restrict__ Wfin, const float* __restrict__ bfin, float* __restrict__ outp)
{
    int g = blockIdx.x, t = threadIdx.x;
    __shared__ float qs[2 * D], ts[D];
    qs[t] = qstar[(size_t)g * 2 * D + t];
    qs[D + t] = qstar[(size_t)g * 2 * D + D + t];
    __syncthreads();

    float acc = blin[t];
    for (int k = 0; k < 2 * D; k++) acc += qs[k] * Wlin[(size_t)k * D + t];
    ts[t] = leaky(acc);
    __syncthreads();

    if (t < L_DIM) {
        float a2 = bfin[t];
        for (int k = 0; k < D; k++) a2 += ts[k] * Wfin[(size_t)k * L_DIM + t];
        outp[(size_t)g * L_DIM + t] = a2;
    }
}

// ---------------------------------------------------------------------------
extern "C" void kernel_launch(void* const* d_in, const int* in_sizes, int n_in,
                              void* d_out, int out_size, void* d_ws, size_t ws_size,
                              hipStream_t stream)
{
    const float* x      = (const float*)d_in[0];
    const int*   ei     = (const int*)d_in[1];
    const int*   batch  = (const int*)d_in[3];
    const float* Wemb   = (const float*)d_in[4];
    const float* bemb   = (const float*)d_in[5];
    const float* Wfirst = (const float*)d_in[6];
    const float* bfirst = (const float*)d_in[7];
    const float* Wl     = (const float*)d_in[8];
    const float* bl     = (const float*)d_in[9];
    const float* Wr     = (const float*)d_in[10];
    const float* gWih   = (const float*)d_in[11];
    const float* gWhh   = (const float*)d_in[12];
    const float* gbih   = (const float*)d_in[13];
    const float* gbhh   = (const float*)d_in[14];
    const float* lWih   = (const float*)d_in[15];
    const float* lWhh   = (const float*)d_in[16];
    const float* lbih   = (const float*)d_in[17];
    const float* lbhh   = (const float*)d_in[18];
    const float* Wlin   = (const float*)d_in[19];
    const float* blin   = (const float*)d_in[20];
    const float* Wfin   = (const float*)d_in[21];
    const float* bfin   = (const float*)d_in[22];
    float* outp = (float*)d_out;

    // ---- workspace carve (256B-aligned slabs), ~33 MB ----
    size_t o = 0;
    char* base = (char*)d_ws;
    auto carve = [&](size_t bytes) { void* p = base + o; o += (bytes + 255) & ~(size_t)255; return p; };
    bf16*  h0     = (bf16*)carve((size_t)N_NODES * D * sizeof(bf16));
    bf16*  h1     = (bf16*)carve((size_t)N_NODES * D * sizeof(bf16));
    int*   offs   = (int*)carve((size_t)SCAN_N * sizeof(int));
    int*   srcs   = (int*)carve((size_t)N_EDGES * sizeof(int));
    int*   bcnt   = (int*)carve((size_t)(NBUCK + 1) * sizeof(int));
    int*   bcur   = (int*)carve((size_t)NBUCK * sizeof(int));
    uint*  ebuf   = (uint*)carve((size_t)N_EDGES * sizeof(uint));
    float* hh     = (float*)carve((size_t)N_GRAPHS * D * sizeof(float));
    float* cc     = (float*)carve((size_t)N_GRAPHS * D * sizeof(float));
    float* qstar  = (float*)carve((size_t)N_GRAPHS * 2 * D * sizeof(float));
    int*   gstart = (int*)carve((size_t)(N_GRAPHS + 1) * sizeof(int));
    short* W1p    = (short*)carve((size_t)256 * 128 * sizeof(short));
    short* Wihp   = (short*)carve((size_t)128 * 384 * sizeof(short));
    short* Whhp   = (short*)carve((size_t)128 * 384 * sizeof(short));
    size_t need = o;

    if (ws_size < need) {
        k_signal<<<(out_size + 255) / 256, 256, 0, stream>>>(outp, out_size);
        return;
    }

    // node MLP -> h0
    k_embed<<<N_NODES / NPE, 128, 0, stream>>>(x, Wemb, bemb, Wfirst, bfirst, h0);

    // all weight packing
    k_pack_all<<<(32768 + 98304) / 256, 256, 0, stream>>>(Wl, Wr, gWih, gWhh, W1p, Wihp, Whhp);

    // bucketed CSR build (LDS-aggregated placement)
    hipMemsetAsync(bcnt, 0, (size_t)((char*)ebuf - (char*)bcnt), stream);
    k_bcount<<<128, 256, 0, stream>>>(ei, bcnt);
    k_bscan<<<1, 64, 0, stream>>>(bcnt);
    k_bfill2<<<(N_EDGES + EPB - 1) / EPB, BFT, 0, stream>>>(ei, bcnt, bcur, ebuf);
    k_csr<<<NBUCK, 256, 0, stream>>>(bcnt, ebuf, offs, srcs);

    // graph segment starts
    k_gstart<<<(N_GRAPHS + 1 + 255) / 256, 256, 0, stream>>>(batch, gstart);

    // 3 message-passing steps
    bf16* hc = h0; bf16* hn = h1;
    for (int s = 0; s < 3; s++) {
        k_gather<<<N_NODES / 4, 256, 0, stream>>>(hc, hn, offs, srcs);
        k_sage_gru_mfma<<<(N_NODES + 63) / 64, 256, 0, stream>>>(
            hc, hn, W1p, Wihp, Whhp, bl, gbih, gbhh);
        bf16* tmp = hc; hc = hn; hn = tmp;
    }

    // Set2Set: merged LSTM+pool, 2 graphs/block
    for (int s = 0; s < 3; s++) {
        k_s2s<<<N_GRAPHS / LG2, 1024, 0, stream>>>(lWih, lWhh, lbih, lbhh,
                                                   hc, gstart, qstar, hh, cc, s == 0);
    }

    k_final<<<N_GRAPHS, 128, 0, stream>>>(qstar, Wlin, blin, Wfin, bfin, outp);
}